// Round 10
// baseline (5096.817 us; speedup 1.0000x reference)
//
#include <hip/hip_runtime.h>

#define BN_SCALE 0.9999950000374997f  // 1/sqrt(1+1e-5)
#define AGENT __HIP_MEMORY_SCOPE_AGENT

// ---------------- device-scope phase barrier (pipeline blocks only) ----------------
__device__ __forceinline__ void phase_barrier(unsigned* ctr, unsigned target) {
  __syncthreads();
  if (threadIdx.x == 0) {
    __threadfence();  // release prior writes device-wide
    __hip_atomic_fetch_add(ctr, 1u, __ATOMIC_ACQ_REL, AGENT);
    while (__hip_atomic_load(ctr, __ATOMIC_ACQUIRE, AGENT) < target) {
      __builtin_amdgcn_s_sleep(8);
    }
  }
  __syncthreads();
  __threadfence();    // acquire for all threads
}

// ---------------- knn task: 4 queries; sq-norm folded; |q|^2 row-shift dropped ----------------
__device__ void knn_task(const float* __restrict__ Q, long qStrideB,
                         const float* __restrict__ Xc, long cStrideB,
                         int C, int Mq, int N, int k, int* __restrict__ idxOut,
                         int b, int q0, char* smem) {
  float* qv = (float*)smem;             // [4][256]
  float* negd = (float*)(smem + 4096);  // [4][2048]
  int tid = threadIdx.x;
  for (int e = tid; e < 4 * C; e += 256) {
    int qq = e / C, c = e % C;
    qv[qq * 256 + c] = Q[(long)b * qStrideB + (long)c * Mq + (q0 + qq)];
  }
  __syncthreads();
  const float* cb = Xc + (long)b * cStrideB;
  for (int m = tid; m < N; m += 256) {
    float d0 = 0.f, d1 = 0.f, d2 = 0.f, d3 = 0.f, sq = 0.f;
    for (int c = 0; c < C; ++c) {
      float xv = cb[(long)c * N + m];
      d0 = fmaf(qv[0 * 256 + c], xv, d0);
      d1 = fmaf(qv[1 * 256 + c], xv, d1);
      d2 = fmaf(qv[2 * 256 + c], xv, d2);
      d3 = fmaf(qv[3 * 256 + c], xv, d3);
      sq = fmaf(xv, xv, sq);
    }
    negd[0 * 2048 + m] = 2.f * d0 - sq;
    negd[1 * 2048 + m] = 2.f * d1 - sq;
    negd[2 * 2048 + m] = 2.f * d2 - sq;
    negd[3 * 2048 + m] = 2.f * d3 - sq;
  }
  __syncthreads();
  int lane = tid & 63, w = tid >> 6;
  float* row = negd + w * 2048;
  int* outp = idxOut + ((long)b * Mq + (q0 + w)) * k;
  for (int kk = 0; kk < k; ++kk) {
    float best = -INFINITY; int bi = N;
    for (int m = lane; m < N; m += 64) {
      float vv = row[m];
      if (vv > best) { best = vv; bi = m; }
    }
    for (int off = 32; off > 0; off >>= 1) {
      float ov = __shfl_xor(best, off);
      int   oi = __shfl_xor(bi, off);
      if (ov > best || (ov == best && oi < bi)) { best = ov; bi = oi; }
    }
    if (lane == (bi & 63)) row[bi] = -INFINITY;
    if (lane == 0) outp[kk] = bi;
  }
}

// ---------------- gemmPS task ----------------
__device__ void gemmPS_task(const float* __restrict__ X, long xStrideB, int C, int Np,
                            const float* __restrict__ W, int ldw, int O,
                            float* __restrict__ PtT, float* __restrict__ StT,
                            int b, int n0, int o0, char* smem) {
  float* Wp = (float*)smem;             // [16][65]
  float* Ws = (float*)(smem + 4160);
  float* Xt = (float*)(smem + 8320);
  int tid = threadIdx.x;
  int to = tid % 16, tn = tid / 16;
  float accP[4][4] = {}, accS[4][4] = {};
  for (int c0 = 0; c0 < C; c0 += 16) {
    for (int e = tid; e < 16 * 64; e += 256) {
      int oo = e / 16, kk = e % 16;
      int c = c0 + kk, o = o0 + oo;
      bool ok = (c < C && o < O);
      Wp[kk * 65 + oo] = ok ? W[(long)o * ldw + c] : 0.f;
      Ws[kk * 65 + oo] = ok ? W[(long)o * ldw + C + c] : 0.f;
    }
    for (int e = tid; e < 16 * 64; e += 256) {
      int kk = e / 64, nn = e % 64;
      int c = c0 + kk, n = n0 + nn;
      Xt[kk * 65 + nn] = (c < C && n < Np) ? X[(long)b * xStrideB + (long)c * Np + n] : 0.f;
    }
    __syncthreads();
    for (int kk = 0; kk < 16; ++kk) {
      float xv[4], wp[4], ws[4];
      for (int i = 0; i < 4; ++i) xv[i] = Xt[kk * 65 + tn + 16 * i];
      for (int j = 0; j < 4; ++j) { wp[j] = Wp[kk * 65 + to + 16 * j]; ws[j] = Ws[kk * 65 + to + 16 * j]; }
      for (int i = 0; i < 4; ++i)
        for (int j = 0; j < 4; ++j) {
          accP[i][j] = fmaf(xv[i], wp[j], accP[i][j]);
          accS[i][j] = fmaf(xv[i], ws[j], accS[i][j]);
        }
    }
    __syncthreads();
  }
  for (int i = 0; i < 4; ++i) {
    int n = n0 + tn + 16 * i;
    if (n >= Np) continue;
    for (int j = 0; j < 4; ++j) {
      int o = o0 + to + 16 * j;
      if (o < O) {
        long off = ((long)b * Np + n) * O + o;
        PtT[off] = accP[i][j];
        StT[off] = accS[i][j];
      }
    }
  }
}

// ---------------- ecfinish task, stage1/2 geometry (o = tid&63, 4 n per task) ----------------
__device__ void ecfA_task(const float* __restrict__ Pt, const float* __restrict__ St,
                          const int* __restrict__ idx, int k, int O, int Np,
                          const float* __restrict__ g, const float* __restrict__ bb,
                          float* __restrict__ outp, long oStrideB, int b, int nbase) {
  int o = threadIdx.x & 63;
  int n = nbase + (threadIdx.x >> 6);
  const float* PtB = Pt + (long)b * Np * O;
  const float* StB = St + (long)b * Np * O;
  const int* ip = idx + ((long)b * Np + n) * k;
  float mx = -INFINITY, mn = INFINITY;
  for (int kk = 0; kk < k; ++kk) {
    float v = PtB[(long)ip[kk] * O + o];
    mx = fmaxf(mx, v); mn = fminf(mn, v);
  }
  float ctrP = PtB[(long)n * O + o];
  float ctrS = StB[(long)n * O + o];
  float gs = g[o] * BN_SCALE;
  float m = (gs >= 0.f) ? mx : mn;
  float h = (ctrS - ctrP + m) * gs + bb[o];
  outp[(long)b * oStrideB + (long)o * Np + n] = h >= 0.f ? h : 0.2f * h;
}

// ---------------- ecfinish task, stage3/4 geometry (o = tid, 1 n per task, O=256) ----------------
__device__ void ecfB_task(const float* __restrict__ Pt, const float* __restrict__ St,
                          const int* __restrict__ idx, int k, int O, int Np,
                          const float* __restrict__ g, const float* __restrict__ bb,
                          float* __restrict__ outp, long oStrideB, int b, int n) {
  int o = threadIdx.x;
  const float* PtB = Pt + (long)b * Np * O;
  const float* StB = St + (long)b * Np * O;
  const int* ip = idx + ((long)b * Np + n) * k;
  float mx = -INFINITY, mn = INFINITY;
  for (int kk = 0; kk < k; ++kk) {
    float v = PtB[(long)ip[kk] * O + o];
    mx = fmaxf(mx, v); mn = fminf(mn, v);
  }
  float ctrP = PtB[(long)n * O + o];
  float ctrS = StB[(long)n * O + o];
  float gs = g[o] * BN_SCALE;
  float m = (gs >= 0.f) ? mx : mn;
  float h = (ctrS - ctrP + m) * gs + bb[o];
  outp[(long)b * oStrideB + (long)o * Np + n] = h >= 0.f ? h : 0.2f * h;
}

// ---------------- gemm_colmax task ----------------
__device__ void colmax_task(const float* __restrict__ X, long xStrideB, int C, int Np,
                            const float* __restrict__ W, int ldw, int O,
                            const float* __restrict__ g, const float* __restrict__ bb,
                            float* __restrict__ partial, int NT,
                            int b, int n0, int o0, int nb, char* smem) {
  float* Wt = (float*)smem;             // [16][65]
  float* Xt = (float*)(smem + 4160);
  int tid = threadIdx.x;
  int to = tid % 16, tn = tid / 16;
  float acc[4][4] = {};
  for (int c0 = 0; c0 < C; c0 += 16) {
    for (int e = tid; e < 16 * 64; e += 256) {
      int oo = e / 16, kk = e % 16;
      int c = c0 + kk, o = o0 + oo;
      Wt[kk * 65 + oo] = (c < C && o < O) ? W[(long)o * ldw + c] : 0.f;
    }
    for (int e = tid; e < 16 * 64; e += 256) {
      int kk = e / 64, nn = e % 64;
      int c = c0 + kk, n = n0 + nn;
      Xt[kk * 65 + nn] = (c < C && n < Np) ? X[(long)b * xStrideB + (long)c * Np + n] : 0.f;
    }
    __syncthreads();
    for (int kk = 0; kk < 16; ++kk) {
      float xv[4], wv[4];
      for (int i = 0; i < 4; ++i) xv[i] = Xt[kk * 65 + tn + 16 * i];
      for (int j = 0; j < 4; ++j) wv[j] = Wt[kk * 65 + to + 16 * j];
      for (int i = 0; i < 4; ++i)
        for (int j = 0; j < 4; ++j) acc[i][j] = fmaf(xv[i], wv[j], acc[i][j]);
    }
    __syncthreads();
  }
  float vm[4];
  for (int j = 0; j < 4; ++j) {
    int o = o0 + to + 16 * j;
    float gs = g[o] * BN_SCALE, bo = bb[o];
    float m = -INFINITY;
    for (int i = 0; i < 4; ++i) {
      float h = acc[i][j] * gs + bo;
      h = h >= 0.f ? h : 0.2f * h;
      m = fmaxf(m, h);
    }
    vm[j] = m;
  }
  for (int j = 0; j < 4; ++j) Xt[tn * 65 + to + 16 * j] = vm[j];
  __syncthreads();
  for (int s = 8; s > 0; s >>= 1) {
    if (tn < s)
      for (int j = 0; j < 4; ++j)
        Xt[tn * 65 + to + 16 * j] = fmaxf(Xt[tn * 65 + to + 16 * j], Xt[(tn + s) * 65 + to + 16 * j]);
    __syncthreads();
  }
  if (tn == 0)
    for (int j = 0; j < 4; ++j) {
      int o = o0 + to + 16 * j;
      partial[((long)b * NT + nb) * O + o] = Xt[0 * 65 + to + 16 * j];
    }
}

// ---------------- fps role: 4 waves, dist[8] in VGPRs, swizzled LDS float4 ----------------
__device__ void fps_role(const float* __restrict__ xyz, int N, int M,
                         int* __restrict__ fpsIdx, float* __restrict__ node1,
                         int b, char* smem) {
  #pragma clang fp contract(off)
  float4* sp4 = (float4*)smem;               // 2048 float4, point n at slot (n&7)*256+(n>>3)
  int* fidx = (int*)(smem + 32768);          // 512 ints
  float* wvs = (float*)(smem + 34816);       // [2][4]
  int*   wis = (int*)(smem + 34848);         // [2][4]
  int tid = threadIdx.x;
  int lane = tid & 63, w = tid >> 6;
  const float* xb = xyz + (long)b * 3 * N;
  for (int n = tid; n < N; n += 256) {
    sp4[((n & 7) << 8) | (n >> 3)] = make_float4(xb[n], xb[N + n], xb[2 * N + n], 0.f);
  }
  __syncthreads();
  float dist[8];
  #pragma unroll
  for (int i = 0; i < 8; ++i) dist[i] = 1e10f;
  int base = tid * 8;
  int last = 0;
  for (int it = 0; it < M; ++it) {
    int p = it & 1;
    if (tid == 0) fidx[it] = last;
    float4 lp = sp4[((last & 7) << 8) | (last >> 3)];
    float best = -INFINITY; int bi = N;
    #pragma unroll
    for (int i = 0; i < 8; ++i) {
      float4 pt = sp4[(i << 8) | tid];
      float dx = pt.x - lp.x, dy = pt.y - lp.y, dz = pt.z - lp.z;
      float dx2 = dx * dx, dy2 = dy * dy, dz2 = dz * dz;
      float d = (dx2 + dy2) + dz2;
      float dn = dist[i];
      if (d < dn) dn = d;
      dist[i] = dn;
      if (dn > best) { best = dn; bi = base + i; }
    }
    float gmax = best;
    #pragma unroll
    for (int off = 32; off > 0; off >>= 1) {
      float ov = __shfl_xor(gmax, off);
      gmax = fmaxf(gmax, ov);
    }
    unsigned long long mm = __ballot(best == gmax);
    int srcLane = (int)(__ffsll((long long)mm) - 1);
    int wbi = __shfl(bi, srcLane);
    if (lane == 0) { wvs[p * 4 + w] = gmax; wis[p * 4 + w] = wbi; }
    __syncthreads();
    float bv = wvs[p * 4 + 0]; int bbi = wis[p * 4 + 0];
    #pragma unroll
    for (int ww = 1; ww < 4; ++ww) {
      float ov = wvs[p * 4 + ww]; int oi = wis[p * 4 + ww];
      if (ov > bv || (ov == bv && oi < bbi)) { bv = ov; bbi = oi; }
    }
    last = bbi;
  }
  for (int e = tid; e < M; e += 256) fpsIdx[(long)b * M + e] = fidx[e];
  for (int e = tid; e < 3 * M; e += 256) {
    int c = e / M, i = e % M;
    int src = fidx[i];
    float4 pt = sp4[((src & 7) << 8) | (src >> 3)];
    node1[(long)b * 3 * M + e] = (c == 0) ? pt.x : (c == 1) ? pt.y : pt.z;
  }
}

// ---------------- head task ----------------
__device__ void head_task(const float* __restrict__ partA, int NTa,
                          const float* __restrict__ partB, int NTb,
                          const float* __restrict__ Wl1, const float* __restrict__ g6, const float* __restrict__ b6,
                          const float* __restrict__ Wl2, const float* __restrict__ bl2,
                          const float* __restrict__ g7, const float* __restrict__ b7,
                          const float* __restrict__ Wl3, const float* __restrict__ bl3,
                          float* __restrict__ logits, int b, char* smem) {
  float* v  = (float*)smem;             // 2048
  float* h1 = (float*)(smem + 8192);    // 512
  float* h2 = (float*)(smem + 10240);   // 256
  int tid = threadIdx.x;
  for (int o = tid; o < 1024; o += 256) {
    float m = -INFINITY;
    for (int t = 0; t < NTa; ++t) m = fmaxf(m, partA[((long)b * NTa + t) * 1024 + o]);
    v[o] = m;
    float m2 = -INFINITY;
    for (int t = 0; t < NTb; ++t) m2 = fmaxf(m2, partB[((long)b * NTb + t) * 1024 + o]);
    v[1024 + o] = m2;
  }
  __syncthreads();
  for (int o = tid; o < 512; o += 256) {
    const float* wr = Wl1 + (long)o * 2048;
    float s = 0.f;
    for (int c = 0; c < 2048; c += 4) {
      float4 w4 = *(const float4*)(wr + c);
      s = fmaf(w4.x, v[c], s); s = fmaf(w4.y, v[c + 1], s);
      s = fmaf(w4.z, v[c + 2], s); s = fmaf(w4.w, v[c + 3], s);
    }
    float h = s * (g6[o] * BN_SCALE) + b6[o];
    h1[o] = h >= 0.f ? h : 0.2f * h;
  }
  __syncthreads();
  for (int o = tid; o < 256; o += 256) {
    const float* wr = Wl2 + (long)o * 512;
    float s = 0.f;
    for (int c = 0; c < 512; c += 4) {
      float4 w4 = *(const float4*)(wr + c);
      s = fmaf(w4.x, h1[c], s); s = fmaf(w4.y, h1[c + 1], s);
      s = fmaf(w4.z, h1[c + 2], s); s = fmaf(w4.w, h1[c + 3], s);
    }
    s += bl2[o];
    float h = s * (g7[o] * BN_SCALE) + b7[o];
    h2[o] = h >= 0.f ? h : 0.2f * h;
  }
  __syncthreads();
  if (tid < 40) {
    const float* wr = Wl3 + (long)tid * 256;
    float s = 0.f;
    for (int c = 0; c < 256; ++c) s = fmaf(wr[c], h2[c], s);
    logits[(long)b * 40 + tid] = s + bl3[tid];
  }
}

// ---------------- MEGA: whole network in one launch ----------------
// blocks 0..7: fps (barrier-free, raises flag ctrs[63]); blocks 8..G-1: 13-phase pipeline.
__global__ void __launch_bounds__(256, 3) mega_kernel(
    const float* x, const float* W1, const float* g1, const float* b1,
    const float* W2, const float* g2, const float* b2,
    const float* W2m, const float* g2m, const float* b2m,
    const float* W3, const float* g3, const float* b3,
    const float* W4, const float* g4, const float* b4,
    const float* W5, const float* g5, const float* b5,
    const float* Wl1, const float* g6, const float* b6,
    const float* Wl2, const float* bl2, const float* g7, const float* b7,
    const float* Wl3, const float* bl3,
    float* outF, float* xt1, float* xm, float* xc,
    float* Pt, float* St, float* partA, float* partB,
    int* idxK, int* fpsI, unsigned* ctrs) {
  extern __shared__ char smem[];
  const int N = 2048, M = 512, K = 20, K2 = 10;
  const int bid = blockIdx.x, tid = threadIdx.x;
  float* logits = outF;
  float* node1  = outF + 320;

  if (bid < 8) {
    fps_role(x, N, M, fpsI, node1, bid, smem);
    __syncthreads();
    if (tid == 0) {
      __threadfence();
      __hip_atomic_fetch_add(&ctrs[63], 1u, __ATOMIC_ACQ_REL, AGENT);
    }
    return;
  }
  const int v = bid - 8;
  const unsigned P = gridDim.x - 8;

  // P0: knn1 (4096) + gemmPS1 (256)
  for (int u = v; u < 4352; u += P) {
    __syncthreads();
    if (u < 4096) knn_task(x, 3 * N, x, 3 * N, 3, N, N, K, idxK, u / 512, (u % 512) * 4, smem);
    else { int u2 = u - 4096; gemmPS_task(x, 3 * N, 3, N, W1, 6, 64, Pt, St, u2 / 32, (u2 % 32) * 64, 0, smem); }
  }
  phase_barrier(&ctrs[0], P);
  // P1: ecfinish1 -> xt1 ch0..63
  for (int u = v; u < 4096; u += P) {
    ecfA_task(Pt, St, idxK, K, 64, N, g1, b1, xt1, (long)128 * N, u / 512, (u % 512) * 4);
  }
  phase_barrier(&ctrs[1], P);
  // P2: knn2 + gemmPS2
  for (int u = v; u < 4352; u += P) {
    __syncthreads();
    if (u < 4096) knn_task(xt1, (long)128 * N, xt1, (long)128 * N, 64, N, N, K, idxK, u / 512, (u % 512) * 4, smem);
    else { int u2 = u - 4096; gemmPS_task(xt1, (long)128 * N, 64, N, W2, 128, 64, Pt, St, u2 / 32, (u2 % 32) * 64, 0, smem); }
  }
  phase_barrier(&ctrs[2], P);
  // P3: ecfinish2 -> xt1 ch64..127
  for (int u = v; u < 4096; u += P) {
    ecfA_task(Pt, St, idxK, K, 64, N, g2, b2, xt1 + (size_t)64 * N, (long)128 * N, u / 512, (u % 512) * 4);
  }
  phase_barrier(&ctrs[3], P);
  // P4: colmaxA -> partA (NT=32)
  for (int u = v; u < 4096; u += P) {
    __syncthreads();
    int nb = u % 32, ob = (u / 32) % 16, b = u / 512;
    colmax_task(xt1, (long)128 * N, 128, N, W2m, 128, 1024, g2m, b2m, partA, 32, b, nb * 64, ob * 64, nb, smem);
  }
  phase_barrier(&ctrs[4], P);
  // wait for fps (flag = 8)
  if (tid == 0) {
    while (__hip_atomic_load(&ctrs[63], __ATOMIC_ACQUIRE, AGENT) < 8u) __builtin_amdgcn_s_sleep(8);
  }
  __syncthreads();
  __threadfence();
  // P5: knn_agg (node1 vs xyz) -> idxK
  for (int u = v; u < 1024; u += P) {
    __syncthreads();
    knn_task(node1, 3 * M, x, 3 * N, 3, M, N, K, idxK, u / 128, (u % 128) * 4, smem);
  }
  phase_barrier(&ctrs[5], P);
  // P6: xmfill (fused nf1 gather + agg gathermax), 2048 units
  for (int u = v; u < 2048; u += P) {
    long t = (long)u * 256 + tid;
    int i = (int)(t % M);
    int c = (int)((t / M) % 128);
    int b = (int)(t / ((long)128 * M));
    const float* xb = xt1 + (long)b * 128 * N + (long)c * N;
    float* xmB = xm + (long)b * 256 * M;
    xmB[(long)c * M + i] = xb[fpsI[(long)b * M + i]];
    const int* ip = idxK + ((long)b * M + i) * K;
    float best = -INFINITY;
    for (int kk = 0; kk < K; ++kk) best = fmaxf(best, xb[ip[kk]]);
    xmB[(long)(128 + c) * M + i] = best;
  }
  phase_barrier(&ctrs[6], P);
  // P7: knn3 (1024) + gemmPS3 (256)
  for (int u = v; u < 1280; u += P) {
    __syncthreads();
    if (u < 1024) knn_task(xm, (long)256 * M, xm, (long)256 * M, 256, M, M, K2, idxK, u / 128, (u % 128) * 4, smem);
    else { int u2 = u - 1024; gemmPS_task(xm, (long)256 * M, 256, M, W3, 512, 256, Pt, St, u2 / 32, (u2 % 8) * 64, ((u2 / 8) % 4) * 64, smem); }
  }
  phase_barrier(&ctrs[7], P);
  // P8: ecfinish3 -> xc ch0..255
  for (int u = v; u < 4096; u += P) {
    ecfB_task(Pt, St, idxK, K2, 256, M, g3, b3, xc, (long)512 * M, u / 512, u % 512);
  }
  phase_barrier(&ctrs[8], P);
  // P9: knn4 (1024) + gemmPS4 (256)
  for (int u = v; u < 1280; u += P) {
    __syncthreads();
    if (u < 1024) knn_task(xc, (long)512 * M, xc, (long)512 * M, 256, M, M, K2, idxK, u / 128, (u % 128) * 4, smem);
    else { int u2 = u - 1024; gemmPS_task(xc, (long)512 * M, 256, M, W4, 512, 256, Pt, St, u2 / 32, (u2 % 8) * 64, ((u2 / 8) % 4) * 64, smem); }
  }
  phase_barrier(&ctrs[9], P);
  // P10: ecfinish4 -> xc ch256..511
  for (int u = v; u < 4096; u += P) {
    ecfB_task(Pt, St, idxK, K2, 256, M, g4, b4, xc + (size_t)256 * M, (long)512 * M, u / 512, u % 512);
  }
  phase_barrier(&ctrs[10], P);
  // P11: colmaxB -> partB (NT=8)
  for (int u = v; u < 1024; u += P) {
    __syncthreads();
    int nb = u % 8, ob = (u / 8) % 16, b = u / 128;
    colmax_task(xc, (long)512 * M, 512, M, W5, 512, 1024, g5, b5, partB, 8, b, nb * 64, ob * 64, nb, smem);
  }
  phase_barrier(&ctrs[11], P);
  // P12: head (8 units)
  for (int u = v; u < 8; u += P) {
    __syncthreads();
    head_task(partA, 32, partB, 8, Wl1, g6, b6, Wl2, bl2, g7, b7, Wl3, bl3, logits, u, smem);
  }
}

extern "C" void kernel_launch(void* const* d_in, const int* in_sizes, int n_in,
                              void* d_out, int out_size, void* d_ws, size_t ws_size,
                              hipStream_t stream) {
  const float* x   = (const float*)d_in[0];
  const float* W1  = (const float*)d_in[1];
  const float* g1  = (const float*)d_in[2];
  const float* b1  = (const float*)d_in[3];
  const float* W2  = (const float*)d_in[4];
  const float* g2  = (const float*)d_in[5];
  const float* b2  = (const float*)d_in[6];
  const float* W2m = (const float*)d_in[7];
  const float* g2m = (const float*)d_in[8];
  const float* b2m = (const float*)d_in[9];
  const float* W3  = (const float*)d_in[10];
  const float* g3  = (const float*)d_in[11];
  const float* b3  = (const float*)d_in[12];
  const float* W4  = (const float*)d_in[13];
  const float* g4  = (const float*)d_in[14];
  const float* b4  = (const float*)d_in[15];
  const float* W5  = (const float*)d_in[16];
  const float* g5  = (const float*)d_in[17];
  const float* b5  = (const float*)d_in[18];
  const float* Wl1 = (const float*)d_in[19];
  const float* g6  = (const float*)d_in[20];
  const float* b6  = (const float*)d_in[21];
  const float* Wl2 = (const float*)d_in[22];
  const float* bl2 = (const float*)d_in[23];
  const float* g7  = (const float*)d_in[24];
  const float* b7  = (const float*)d_in[25];
  const float* Wl3 = (const float*)d_in[26];
  const float* bl3 = (const float*)d_in[27];
  float* outF = (float*)d_out;

  const int B = 8, N = 2048, K = 20, M = 512;

  float* ws    = (float*)d_ws;
  float* xt1   = ws;                               // (B,128,N)
  float* xm    = xt1 + (size_t)B * 128 * N;        // (B,256,M)
  float* xc    = xm  + (size_t)B * 256 * M;        // (B,512,M)
  float* Pt    = xc  + (size_t)B * 512 * M;        // max(B*N*64, B*M*256)
  float* St    = Pt  + (size_t)B * N * 64;
  float* partA = St  + (size_t)B * N * 64;         // (B,32,1024)
  float* partB = partA + (size_t)B * 32 * 1024;    // (B,8,1024)
  int*   idxK  = (int*)(partB + (size_t)B * 8 * 1024);  // (B,N,K)
  int*   fpsI  = idxK + (size_t)B * N * K;         // (B,M)
  unsigned* ctrs = (unsigned*)(fpsI + (size_t)B * M);   // 64 counters

  hipMemsetAsync(ctrs, 0, 64 * sizeof(unsigned), stream);

  // G=768 (3 blocks/CU: LDS 3*36864=110KB<160KB, 12 waves/CU, VGPR capped by launch_bounds)
  mega_kernel<<<dim3(768), dim3(256), 36864, stream>>>(
      x, W1, g1, b1, W2, g2, b2, W2m, g2m, b2m, W3, g3, b3, W4, g4, b4, W5, g5, b5,
      Wl1, g6, b6, Wl2, bl2, g7, b7, Wl3, bl3,
      outF, xt1, xm, xc, Pt, St, partA, partB, idxK, fpsI, ctrs);
}

// Round 11
// 4687.287 us; speedup vs baseline: 1.0874x; 1.0874x over previous
//
#include <hip/hip_runtime.h>

#define BN_SCALE 0.9999950000374997f  // 1/sqrt(1+1e-5)

// ================= device task functions (verified in R9 mega, barriers removed) =================

// knn task: 4 queries; candidate sq-norm folded; |q|^2 row-shift dropped (top_k invariant)
__device__ void knn_task(const float* __restrict__ Q, long qStrideB,
                         const float* __restrict__ Xc, long cStrideB,
                         int C, int Mq, int N, int k, int* __restrict__ idxOut,
                         int b, int q0, char* smem) {
  float* qv = (float*)smem;             // [4][256]
  float* negd = (float*)(smem + 4096);  // [4][2048]
  int tid = threadIdx.x;
  for (int e = tid; e < 4 * C; e += 256) {
    int qq = e / C, c = e % C;
    qv[qq * 256 + c] = Q[(long)b * qStrideB + (long)c * Mq + (q0 + qq)];
  }
  __syncthreads();
  const float* cb = Xc + (long)b * cStrideB;
  for (int m = tid; m < N; m += 256) {
    float d0 = 0.f, d1 = 0.f, d2 = 0.f, d3 = 0.f, sq = 0.f;
    for (int c = 0; c < C; ++c) {
      float xv = cb[(long)c * N + m];
      d0 = fmaf(qv[0 * 256 + c], xv, d0);
      d1 = fmaf(qv[1 * 256 + c], xv, d1);
      d2 = fmaf(qv[2 * 256 + c], xv, d2);
      d3 = fmaf(qv[3 * 256 + c], xv, d3);
      sq = fmaf(xv, xv, sq);
    }
    negd[0 * 2048 + m] = 2.f * d0 - sq;
    negd[1 * 2048 + m] = 2.f * d1 - sq;
    negd[2 * 2048 + m] = 2.f * d2 - sq;
    negd[3 * 2048 + m] = 2.f * d3 - sq;
  }
  __syncthreads();
  int lane = tid & 63, w = tid >> 6;
  float* row = negd + w * 2048;
  int* outp = idxOut + ((long)b * Mq + (q0 + w)) * k;
  for (int kk = 0; kk < k; ++kk) {
    float best = -INFINITY; int bi = N;
    for (int m = lane; m < N; m += 64) {
      float vv = row[m];
      if (vv > best) { best = vv; bi = m; }
    }
    for (int off = 32; off > 0; off >>= 1) {
      float ov = __shfl_xor(best, off);
      int   oi = __shfl_xor(bi, off);
      if (ov > best || (ov == best && oi < bi)) { best = ov; bi = oi; }
    }
    if (lane == (bi & 63)) row[bi] = -INFINITY;
    if (lane == 0) outp[kk] = bi;
  }
}

// gemmPS task: both halves of edge-conv weight in one pass
__device__ void gemmPS_task(const float* __restrict__ X, long xStrideB, int C, int Np,
                            const float* __restrict__ W, int ldw, int O,
                            float* __restrict__ PtT, float* __restrict__ StT,
                            int b, int n0, int o0, char* smem) {
  float* Wp = (float*)smem;
  float* Ws = (float*)(smem + 4160);
  float* Xt = (float*)(smem + 8320);
  int tid = threadIdx.x;
  int to = tid % 16, tn = tid / 16;
  float accP[4][4] = {}, accS[4][4] = {};
  for (int c0 = 0; c0 < C; c0 += 16) {
    for (int e = tid; e < 16 * 64; e += 256) {
      int oo = e / 16, kk = e % 16;
      int c = c0 + kk, o = o0 + oo;
      bool ok = (c < C && o < O);
      Wp[kk * 65 + oo] = ok ? W[(long)o * ldw + c] : 0.f;
      Ws[kk * 65 + oo] = ok ? W[(long)o * ldw + C + c] : 0.f;
    }
    for (int e = tid; e < 16 * 64; e += 256) {
      int kk = e / 64, nn = e % 64;
      int c = c0 + kk, n = n0 + nn;
      Xt[kk * 65 + nn] = (c < C && n < Np) ? X[(long)b * xStrideB + (long)c * Np + n] : 0.f;
    }
    __syncthreads();
    for (int kk = 0; kk < 16; ++kk) {
      float xv[4], wp[4], ws[4];
      for (int i = 0; i < 4; ++i) xv[i] = Xt[kk * 65 + tn + 16 * i];
      for (int j = 0; j < 4; ++j) { wp[j] = Wp[kk * 65 + to + 16 * j]; ws[j] = Ws[kk * 65 + to + 16 * j]; }
      for (int i = 0; i < 4; ++i)
        for (int j = 0; j < 4; ++j) {
          accP[i][j] = fmaf(xv[i], wp[j], accP[i][j]);
          accS[i][j] = fmaf(xv[i], ws[j], accS[i][j]);
        }
    }
    __syncthreads();
  }
  for (int i = 0; i < 4; ++i) {
    int n = n0 + tn + 16 * i;
    if (n >= Np) continue;
    for (int j = 0; j < 4; ++j) {
      int o = o0 + to + 16 * j;
      if (o < O) {
        long off = ((long)b * Np + n) * O + o;
        PtT[off] = accP[i][j];
        StT[off] = accS[i][j];
      }
    }
  }
}

// colmax task (one 64x64 tile), partial[b][nb][o]
__device__ void colmax_task(const float* __restrict__ X, long xStrideB, int C, int Np,
                            const float* __restrict__ W, int ldw, int O,
                            const float* __restrict__ g, const float* __restrict__ bb,
                            float* __restrict__ partial, int NT,
                            int b, int n0, int o0, int nb, char* smem) {
  float* Wt = (float*)smem;
  float* Xt = (float*)(smem + 4160);
  int tid = threadIdx.x;
  int to = tid % 16, tn = tid / 16;
  float acc[4][4] = {};
  for (int c0 = 0; c0 < C; c0 += 16) {
    for (int e = tid; e < 16 * 64; e += 256) {
      int oo = e / 16, kk = e % 16;
      int c = c0 + kk, o = o0 + oo;
      Wt[kk * 65 + oo] = (c < C && o < O) ? W[(long)o * ldw + c] : 0.f;
    }
    for (int e = tid; e < 16 * 64; e += 256) {
      int kk = e / 64, nn = e % 64;
      int c = c0 + kk, n = n0 + nn;
      Xt[kk * 65 + nn] = (c < C && n < Np) ? X[(long)b * xStrideB + (long)c * Np + n] : 0.f;
    }
    __syncthreads();
    for (int kk = 0; kk < 16; ++kk) {
      float xv[4], wv[4];
      for (int i = 0; i < 4; ++i) xv[i] = Xt[kk * 65 + tn + 16 * i];
      for (int j = 0; j < 4; ++j) wv[j] = Wt[kk * 65 + to + 16 * j];
      for (int i = 0; i < 4; ++i)
        for (int j = 0; j < 4; ++j) acc[i][j] = fmaf(xv[i], wv[j], acc[i][j]);
    }
    __syncthreads();
  }
  float vm[4];
  for (int j = 0; j < 4; ++j) {
    int o = o0 + to + 16 * j;
    float gs = g[o] * BN_SCALE, bo = bb[o];
    float m = -INFINITY;
    for (int i = 0; i < 4; ++i) {
      float h = acc[i][j] * gs + bo;
      h = h >= 0.f ? h : 0.2f * h;
      m = fmaxf(m, h);
    }
    vm[j] = m;
  }
  for (int j = 0; j < 4; ++j) Xt[tn * 65 + to + 16 * j] = vm[j];
  __syncthreads();
  for (int s = 8; s > 0; s >>= 1) {
    if (tn < s)
      for (int j = 0; j < 4; ++j)
        Xt[tn * 65 + to + 16 * j] = fmaxf(Xt[tn * 65 + to + 16 * j], Xt[(tn + s) * 65 + to + 16 * j]);
    __syncthreads();
  }
  if (tn == 0)
    for (int j = 0; j < 4; ++j) {
      int o = o0 + to + 16 * j;
      partial[((long)b * NT + nb) * O + o] = Xt[0 * 65 + to + 16 * j];
    }
}

// fps role: 4 waves, dist[8] in VGPRs, swizzled LDS float4 coords
__device__ void fps_role(const float* __restrict__ xyz, int N, int M,
                         int* __restrict__ fpsIdx, float* __restrict__ node1,
                         int b, char* smem) {
  #pragma clang fp contract(off)
  float4* sp4 = (float4*)smem;               // 2048 float4, point n at slot (n&7)*256+(n>>3)
  int* fidx = (int*)(smem + 32768);          // 512 ints
  float* wvs = (float*)(smem + 34816);       // [2][4]
  int*   wis = (int*)(smem + 34848);         // [2][4]
  int tid = threadIdx.x;
  int lane = tid & 63, w = tid >> 6;
  const float* xb = xyz + (long)b * 3 * N;
  for (int n = tid; n < N; n += 256) {
    sp4[((n & 7) << 8) | (n >> 3)] = make_float4(xb[n], xb[N + n], xb[2 * N + n], 0.f);
  }
  __syncthreads();
  float dist[8];
  #pragma unroll
  for (int i = 0; i < 8; ++i) dist[i] = 1e10f;
  int base = tid * 8;
  int last = 0;
  for (int it = 0; it < M; ++it) {
    int p = it & 1;
    if (tid == 0) fidx[it] = last;
    float4 lp = sp4[((last & 7) << 8) | (last >> 3)];
    float best = -INFINITY; int bi = N;
    #pragma unroll
    for (int i = 0; i < 8; ++i) {
      float4 pt = sp4[(i << 8) | tid];
      float dx = pt.x - lp.x, dy = pt.y - lp.y, dz = pt.z - lp.z;
      float dx2 = dx * dx, dy2 = dy * dy, dz2 = dz * dz;
      float d = (dx2 + dy2) + dz2;
      float dn = dist[i];
      if (d < dn) dn = d;
      dist[i] = dn;
      if (dn > best) { best = dn; bi = base + i; }
    }
    float gmax = best;
    #pragma unroll
    for (int off = 32; off > 0; off >>= 1) {
      float ov = __shfl_xor(gmax, off);
      gmax = fmaxf(gmax, ov);
    }
    unsigned long long mm = __ballot(best == gmax);
    int srcLane = (int)(__ffsll((long long)mm) - 1);
    int wbi = __shfl(bi, srcLane);
    if (lane == 0) { wvs[p * 4 + w] = gmax; wis[p * 4 + w] = wbi; }
    __syncthreads();
    float bv = wvs[p * 4 + 0]; int bbi = wis[p * 4 + 0];
    #pragma unroll
    for (int ww = 1; ww < 4; ++ww) {
      float ov = wvs[p * 4 + ww]; int oi = wis[p * 4 + ww];
      if (ov > bv || (ov == bv && oi < bbi)) { bv = ov; bbi = oi; }
    }
    last = bbi;
  }
  for (int e = tid; e < M; e += 256) fpsIdx[(long)b * M + e] = fidx[e];
  for (int e = tid; e < 3 * M; e += 256) {
    int c = e / M, i = e % M;
    int src = fidx[i];
    float4 pt = sp4[((src & 7) << 8) | (src >> 3)];
    node1[(long)b * 3 * M + e] = (c == 0) ? pt.x : (c == 1) ? pt.y : pt.z;
  }
}

// ================= fused launch shells (role split by blockIdx, NO cross-block sync) =================

// stage1: blocks [0,8) fps | [8,4104) knn1 | [4104,4360) gemmPS1   (all read x; disjoint writes)
__global__ void __launch_bounds__(256) stage1_kernel(const float* __restrict__ x,
                                                     const float* __restrict__ W1,
                                                     float* Pt, float* St,
                                                     int* idxK, int* fpsI, float* node1) {
  __shared__ __align__(16) char smem[36864];
  int bid = blockIdx.x;
  if (bid < 8) {
    fps_role(x, 2048, 512, fpsI, node1, bid, smem);
  } else if (bid < 8 + 4096) {
    int u = bid - 8;
    knn_task(x, 3 * 2048, x, 3 * 2048, 3, 2048, 2048, 20, idxK, u / 512, (u % 512) * 4, smem);
  } else {
    int u = bid - 8 - 4096;
    gemmPS_task(x, 3 * 2048, 3, 2048, W1, 6, 64, Pt, St, u / 32, (u % 32) * 64, 0, smem);
  }
}

// stage2: [0,4096) knn2 | [4096,4352) gemmPS2 | [4352,5376) knn_agg -> idxAgg
__global__ void __launch_bounds__(256) stage2_kernel(const float* __restrict__ x,
                                                     const float* __restrict__ xt1,
                                                     const float* __restrict__ node1,
                                                     const float* __restrict__ W2,
                                                     float* Pt, float* St,
                                                     int* idxK, int* idxAgg) {
  __shared__ __align__(16) char smem[36864];
  int bid = blockIdx.x;
  if (bid < 4096) {
    knn_task(xt1, (long)128 * 2048, xt1, (long)128 * 2048, 64, 2048, 2048, 20, idxK,
             bid / 512, (bid % 512) * 4, smem);
  } else if (bid < 4352) {
    int u = bid - 4096;
    gemmPS_task(xt1, (long)128 * 2048, 64, 2048, W2, 128, 64, Pt, St, u / 32, (u % 32) * 64, 0, smem);
  } else {
    int u = bid - 4352;
    knn_task(node1, 3 * 512, x, 3 * 2048, 3, 512, 2048, 20, idxAgg, u / 128, (u % 128) * 4, smem);
  }
}

// mid: [0,4096) colmaxA -> partA | [4096,6144) xmfill -> xm
__global__ void __launch_bounds__(256) mid_kernel(const float* __restrict__ xt1,
                                                  const float* __restrict__ W2m,
                                                  const float* __restrict__ g2m, const float* __restrict__ b2m,
                                                  float* partA,
                                                  const int* __restrict__ fpsI, const int* __restrict__ idxAgg,
                                                  float* xm) {
  __shared__ __align__(16) char smem[36864];
  int bid = blockIdx.x;
  const int N = 2048, M = 512, K = 20;
  if (bid < 4096) {
    int b = bid / 512, rem = bid % 512;
    int nb = rem % 32, ob = rem / 32;
    colmax_task(xt1, (long)128 * N, 128, N, W2m, 128, 1024, g2m, b2m, partA, 32, b, nb * 64, ob * 64, nb, smem);
  } else {
    int u = bid - 4096;
    long t = (long)u * 256 + threadIdx.x;
    int i = (int)(t % M);
    int c = (int)((t / M) % 128);
    int b = (int)(t / ((long)128 * M));
    const float* xb = xt1 + (long)b * 128 * N + (long)c * N;
    float* xmB = xm + (long)b * 256 * M;
    xmB[(long)c * M + i] = xb[fpsI[(long)b * M + i]];
    const int* ip = idxAgg + ((long)b * M + i) * K;
    float best = -INFINITY;
    for (int kk = 0; kk < K; ++kk) best = fmaxf(best, xb[ip[kk]]);
    xmB[(long)(128 + c) * M + i] = best;
  }
}

// stage34: [0,1024) knn (C=256) | [1024,1280) gemmPS (O=256)
__global__ void __launch_bounds__(256) stage34_kernel(const float* __restrict__ Xin, long xStrideB,
                                                      const float* __restrict__ W,
                                                      float* Pt, float* St, int* idxK) {
  __shared__ __align__(16) char smem[36864];
  int bid = blockIdx.x;
  if (bid < 1024) {
    knn_task(Xin, xStrideB, Xin, xStrideB, 256, 512, 512, 10, idxK, bid / 128, (bid % 128) * 4, smem);
  } else {
    int u = bid - 1024;
    gemmPS_task(Xin, xStrideB, 256, 512, W, 512, 256, Pt, St, u / 32, (u % 8) * 64, ((u / 8) % 4) * 64, smem);
  }
}

// ================= standalone kernels (unchanged from R8) =================

__global__ void ecfinish_kernel(const float* __restrict__ Pt, const float* __restrict__ St,
                                const int* __restrict__ idx, int k, int O, int Np,
                                const float* __restrict__ g, const float* __restrict__ bb,
                                float* __restrict__ outp, long oStrideB) {
  int b = blockIdx.y;
  int n = blockIdx.x * blockDim.y + threadIdx.y;
  int o = threadIdx.x;
  const float* PtB = Pt + (long)b * Np * O;
  const float* StB = St + (long)b * Np * O;
  const int* ip = idx + ((long)b * Np + n) * k;
  float mx = -INFINITY, mn = INFINITY;
  for (int kk = 0; kk < k; ++kk) {
    float v = PtB[(long)ip[kk] * O + o];
    mx = fmaxf(mx, v); mn = fminf(mn, v);
  }
  float ctrP = PtB[(long)n * O + o];
  float ctrS = StB[(long)n * O + o];
  float gs = g[o] * BN_SCALE;
  float m = (gs >= 0.f) ? mx : mn;
  float h = (ctrS - ctrP + m) * gs + bb[o];
  outp[(long)b * oStrideB + (long)o * Np + n] = h >= 0.f ? h : 0.2f * h;
}

__global__ void gemm_colmax_kernel(const float* __restrict__ X, int xStrideB, int C, int Np,
                                   const float* __restrict__ W, int ldw, int O,
                                   const float* __restrict__ g, const float* __restrict__ bb,
                                   float* __restrict__ partial) {
  __shared__ __align__(16) char smem[8320];
  int b = blockIdx.z;
  int nb = blockIdx.x, ob = blockIdx.y;
  colmax_task(X, xStrideB, C, Np, W, ldw, O, g, bb, partial, gridDim.x, b, nb * 64, ob * 64, nb, smem);
}

__global__ void head_kernel(const float* __restrict__ partA, int NTa,
                            const float* __restrict__ partB, int NTb,
                            const float* __restrict__ Wl1, const float* __restrict__ g6, const float* __restrict__ b6,
                            const float* __restrict__ Wl2, const float* __restrict__ bl2,
                            const float* __restrict__ g7, const float* __restrict__ b7,
                            const float* __restrict__ Wl3, const float* __restrict__ bl3,
                            float* __restrict__ logits) {
  __shared__ float v[2048];
  __shared__ float h1[512];
  __shared__ float h2[256];
  int b = blockIdx.x, tid = threadIdx.x;
  for (int o = tid; o < 1024; o += 256) {
    float m = -INFINITY;
    for (int t = 0; t < NTa; ++t) m = fmaxf(m, partA[((long)b * NTa + t) * 1024 + o]);
    v[o] = m;
    float m2 = -INFINITY;
    for (int t = 0; t < NTb; ++t) m2 = fmaxf(m2, partB[((long)b * NTb + t) * 1024 + o]);
    v[1024 + o] = m2;
  }
  __syncthreads();
  for (int o = tid; o < 512; o += 256) {
    const float* wr = Wl1 + (long)o * 2048;
    float s = 0.f;
    for (int c = 0; c < 2048; c += 4) {
      float4 w4 = *(const float4*)(wr + c);
      s = fmaf(w4.x, v[c], s); s = fmaf(w4.y, v[c + 1], s);
      s = fmaf(w4.z, v[c + 2], s); s = fmaf(w4.w, v[c + 3], s);
    }
    float h = s * (g6[o] * BN_SCALE) + b6[o];
    h1[o] = h >= 0.f ? h : 0.2f * h;
  }
  __syncthreads();
  for (int o = tid; o < 256; o += 256) {
    const float* wr = Wl2 + (long)o * 512;
    float s = 0.f;
    for (int c = 0; c < 512; c += 4) {
      float4 w4 = *(const float4*)(wr + c);
      s = fmaf(w4.x, h1[c], s); s = fmaf(w4.y, h1[c + 1], s);
      s = fmaf(w4.z, h1[c + 2], s); s = fmaf(w4.w, h1[c + 3], s);
    }
    s += bl2[o];
    float h = s * (g7[o] * BN_SCALE) + b7[o];
    h2[o] = h >= 0.f ? h : 0.2f * h;
  }
  __syncthreads();
  if (tid < 40) {
    const float* wr = Wl3 + (long)tid * 256;
    float s = 0.f;
    for (int c = 0; c < 256; ++c) s = fmaf(wr[c], h2[c], s);
    logits[(long)b * 40 + tid] = s + bl3[tid];
  }
}

extern "C" void kernel_launch(void* const* d_in, const int* in_sizes, int n_in,
                              void* d_out, int out_size, void* d_ws, size_t ws_size,
                              hipStream_t stream) {
  const float* x   = (const float*)d_in[0];
  const float* W1  = (const float*)d_in[1];
  const float* g1  = (const float*)d_in[2];
  const float* b1  = (const float*)d_in[3];
  const float* W2  = (const float*)d_in[4];
  const float* g2  = (const float*)d_in[5];
  const float* b2  = (const float*)d_in[6];
  const float* W2m = (const float*)d_in[7];
  const float* g2m = (const float*)d_in[8];
  const float* b2m = (const float*)d_in[9];
  const float* W3  = (const float*)d_in[10];
  const float* g3  = (const float*)d_in[11];
  const float* b3  = (const float*)d_in[12];
  const float* W4  = (const float*)d_in[13];
  const float* g4  = (const float*)d_in[14];
  const float* b4  = (const float*)d_in[15];
  const float* W5  = (const float*)d_in[16];
  const float* g5  = (const float*)d_in[17];
  const float* b5  = (const float*)d_in[18];
  const float* Wl1 = (const float*)d_in[19];
  const float* g6  = (const float*)d_in[20];
  const float* b6  = (const float*)d_in[21];
  const float* Wl2 = (const float*)d_in[22];
  const float* bl2 = (const float*)d_in[23];
  const float* g7  = (const float*)d_in[24];
  const float* b7  = (const float*)d_in[25];
  const float* Wl3 = (const float*)d_in[26];
  const float* bl3 = (const float*)d_in[27];
  float* outF = (float*)d_out;

  const int B = 8, N = 2048, K = 20, M = 512, K2 = 10;

  float* ws     = (float*)d_ws;
  float* xt1    = ws;                               // (B,128,N)
  float* xm     = xt1 + (size_t)B * 128 * N;        // (B,256,M)
  float* xc     = xm  + (size_t)B * 256 * M;        // (B,512,M)
  float* Pt     = xc  + (size_t)B * 512 * M;        // max(B*N*64, B*M*256)
  float* St     = Pt  + (size_t)B * N * 64;
  float* partA  = St  + (size_t)B * N * 64;         // (B,32,1024)
  float* partB  = partA + (size_t)B * 32 * 1024;    // (B,8,1024)
  int*   idxK   = (int*)(partB + (size_t)B * 8 * 1024);  // (B,N,K)
  int*   fpsI   = idxK + (size_t)B * N * K;         // (B,M)
  int*   idxAgg = fpsI + (size_t)B * M;             // (B,M,K)

  float* logits = outF;        // (B,40)
  float* node1  = outF + 320;  // (B,3,M)

  dim3 t256(256);

  // L1: fps + knn1 + gemmPS1 (all independent, read x)
  stage1_kernel<<<dim3(8 + 4096 + 256), t256, 0, stream>>>(x, W1, Pt, St, idxK, fpsI, node1);
  // ecf1 -> xt1 ch0..63
  ecfinish_kernel<<<dim3(N / 4, B), dim3(64, 4), 0, stream>>>(Pt, St, idxK, K, 64, N, g1, b1, xt1, (long)128 * N);
  // L2: knn2 + gemmPS2 + knn_agg (independent; knn_agg -> idxAgg)
  stage2_kernel<<<dim3(4096 + 256 + 1024), t256, 0, stream>>>(x, xt1, node1, W2, Pt, St, idxK, idxAgg);
  // ecf2 -> xt1 ch64..127
  ecfinish_kernel<<<dim3(N / 4, B), dim3(64, 4), 0, stream>>>(Pt, St, idxK, K, 64, N, g2, b2,
                                                              xt1 + (size_t)64 * N, (long)128 * N);
  // L3: colmaxA + xmfill (independent)
  mid_kernel<<<dim3(4096 + 2048), t256, 0, stream>>>(xt1, W2m, g2m, b2m, partA, fpsI, idxAgg, xm);
  // L4: knn3 + gemmPS3
  stage34_kernel<<<dim3(1024 + 256), t256, 0, stream>>>(xm, (long)256 * M, W3, Pt, St, idxK);
  // ecf3 -> xc ch0..255
  ecfinish_kernel<<<dim3(M, B), dim3(256, 1), 0, stream>>>(Pt, St, idxK, K2, 256, M, g3, b3, xc, (long)512 * M);
  // L5: knn4 + gemmPS4
  stage34_kernel<<<dim3(1024 + 256), t256, 0, stream>>>(xc, (long)512 * M, W4, Pt, St, idxK);
  // ecf4 -> xc ch256..511
  ecfinish_kernel<<<dim3(M, B), dim3(256, 1), 0, stream>>>(Pt, St, idxK, K2, 256, M, g4, b4,
                                                           xc + (size_t)256 * M, (long)512 * M);
  // colmaxB -> partB
  gemm_colmax_kernel<<<dim3(M / 64, 1024 / 64, B), t256, 0, stream>>>(xc, 512 * M, 512, M, W5, 512, 1024,
                                                                      g5, b5, partB);
  // head (fused colmax_finish + MLP)
  head_kernel<<<dim3(B), t256, 0, stream>>>(partA, 32, partB, 8,
                                            Wl1, g6, b6, Wl2, bl2, g7, b7, Wl3, bl3, logits);
}

// Round 12
// 4324.726 us; speedup vs baseline: 1.1785x; 1.0838x over previous
//
#include <hip/hip_runtime.h>

#define BN_SCALE 0.9999950000374997f  // 1/sqrt(1+1e-5)

// ================= device task functions (verified R8/R9) =================

// knn task: 4 queries; candidate sq-norm folded; |q|^2 row-shift dropped (top_k invariant)
__device__ void knn_task(const float* __restrict__ Q, long qStrideB,
                         const float* __restrict__ Xc, long cStrideB,
                         int C, int Mq, int N, int k, int* __restrict__ idxOut,
                         int b, int q0, char* smem) {
  float* qv = (float*)smem;             // [4][256]
  float* negd = (float*)(smem + 4096);  // [4][2048]
  int tid = threadIdx.x;
  for (int e = tid; e < 4 * C; e += 256) {
    int qq = e / C, c = e % C;
    qv[qq * 256 + c] = Q[(long)b * qStrideB + (long)c * Mq + (q0 + qq)];
  }
  __syncthreads();
  const float* cb = Xc + (long)b * cStrideB;
  for (int m = tid; m < N; m += 256) {
    float d0 = 0.f, d1 = 0.f, d2 = 0.f, d3 = 0.f, sq = 0.f;
    for (int c = 0; c < C; ++c) {
      float xv = cb[(long)c * N + m];
      d0 = fmaf(qv[0 * 256 + c], xv, d0);
      d1 = fmaf(qv[1 * 256 + c], xv, d1);
      d2 = fmaf(qv[2 * 256 + c], xv, d2);
      d3 = fmaf(qv[3 * 256 + c], xv, d3);
      sq = fmaf(xv, xv, sq);
    }
    negd[0 * 2048 + m] = 2.f * d0 - sq;
    negd[1 * 2048 + m] = 2.f * d1 - sq;
    negd[2 * 2048 + m] = 2.f * d2 - sq;
    negd[3 * 2048 + m] = 2.f * d3 - sq;
  }
  __syncthreads();
  int lane = tid & 63, w = tid >> 6;
  float* row = negd + w * 2048;
  int* outp = idxOut + ((long)b * Mq + (q0 + w)) * k;
  for (int kk = 0; kk < k; ++kk) {
    float best = -INFINITY; int bi = N;
    for (int m = lane; m < N; m += 64) {
      float vv = row[m];
      if (vv > best) { best = vv; bi = m; }
    }
    for (int off = 32; off > 0; off >>= 1) {
      float ov = __shfl_xor(best, off);
      int   oi = __shfl_xor(bi, off);
      if (ov > best || (ov == best && oi < bi)) { best = ov; bi = oi; }
    }
    if (lane == (bi & 63)) row[bi] = -INFINITY;
    if (lane == 0) outp[kk] = bi;
  }
}

// gemmPS task: both halves of edge-conv weight in one pass
__device__ void gemmPS_task(const float* __restrict__ X, long xStrideB, int C, int Np,
                            const float* __restrict__ W, int ldw, int O,
                            float* __restrict__ PtT, float* __restrict__ StT,
                            int b, int n0, int o0, char* smem) {
  float* Wp = (float*)smem;
  float* Ws = (float*)(smem + 4160);
  float* Xt = (float*)(smem + 8320);
  int tid = threadIdx.x;
  int to = tid % 16, tn = tid / 16;
  float accP[4][4] = {}, accS[4][4] = {};
  for (int c0 = 0; c0 < C; c0 += 16) {
    for (int e = tid; e < 16 * 64; e += 256) {
      int oo = e / 16, kk = e % 16;
      int c = c0 + kk, o = o0 + oo;
      bool ok = (c < C && o < O);
      Wp[kk * 65 + oo] = ok ? W[(long)o * ldw + c] : 0.f;
      Ws[kk * 65 + oo] = ok ? W[(long)o * ldw + C + c] : 0.f;
    }
    for (int e = tid; e < 16 * 64; e += 256) {
      int kk = e / 64, nn = e % 64;
      int c = c0 + kk, n = n0 + nn;
      Xt[kk * 65 + nn] = (c < C && n < Np) ? X[(long)b * xStrideB + (long)c * Np + n] : 0.f;
    }
    __syncthreads();
    for (int kk = 0; kk < 16; ++kk) {
      float xv[4], wp[4], ws[4];
      for (int i = 0; i < 4; ++i) xv[i] = Xt[kk * 65 + tn + 16 * i];
      for (int j = 0; j < 4; ++j) { wp[j] = Wp[kk * 65 + to + 16 * j]; ws[j] = Ws[kk * 65 + to + 16 * j]; }
      for (int i = 0; i < 4; ++i)
        for (int j = 0; j < 4; ++j) {
          accP[i][j] = fmaf(xv[i], wp[j], accP[i][j]);
          accS[i][j] = fmaf(xv[i], ws[j], accS[i][j]);
        }
    }
    __syncthreads();
  }
  for (int i = 0; i < 4; ++i) {
    int n = n0 + tn + 16 * i;
    if (n >= Np) continue;
    for (int j = 0; j < 4; ++j) {
      int o = o0 + to + 16 * j;
      if (o < O) {
        long off = ((long)b * Np + n) * O + o;
        PtT[off] = accP[i][j];
        StT[off] = accS[i][j];
      }
    }
  }
}

// colmax task (one 64x64 tile), partial[b][nb][o]
__device__ void colmax_task(const float* __restrict__ X, long xStrideB, int C, int Np,
                            const float* __restrict__ W, int ldw, int O,
                            const float* __restrict__ g, const float* __restrict__ bb,
                            float* __restrict__ partial, int NT,
                            int b, int n0, int o0, int nb, char* smem) {
  float* Wt = (float*)smem;
  float* Xt = (float*)(smem + 4160);
  int tid = threadIdx.x;
  int to = tid % 16, tn = tid / 16;
  float acc[4][4] = {};
  for (int c0 = 0; c0 < C; c0 += 16) {
    for (int e = tid; e < 16 * 64; e += 256) {
      int oo = e / 16, kk = e % 16;
      int c = c0 + kk, o = o0 + oo;
      Wt[kk * 65 + oo] = (c < C && o < O) ? W[(long)o * ldw + c] : 0.f;
    }
    for (int e = tid; e < 16 * 64; e += 256) {
      int kk = e / 64, nn = e % 64;
      int c = c0 + kk, n = n0 + nn;
      Xt[kk * 65 + nn] = (c < C && n < Np) ? X[(long)b * xStrideB + (long)c * Np + n] : 0.f;
    }
    __syncthreads();
    for (int kk = 0; kk < 16; ++kk) {
      float xv[4], wv[4];
      for (int i = 0; i < 4; ++i) xv[i] = Xt[kk * 65 + tn + 16 * i];
      for (int j = 0; j < 4; ++j) wv[j] = Wt[kk * 65 + to + 16 * j];
      for (int i = 0; i < 4; ++i)
        for (int j = 0; j < 4; ++j) acc[i][j] = fmaf(xv[i], wv[j], acc[i][j]);
    }
    __syncthreads();
  }
  float vm[4];
  for (int j = 0; j < 4; ++j) {
    int o = o0 + to + 16 * j;
    float gs = g[o] * BN_SCALE, bo = bb[o];
    float m = -INFINITY;
    for (int i = 0; i < 4; ++i) {
      float h = acc[i][j] * gs + bo;
      h = h >= 0.f ? h : 0.2f * h;
      m = fmaxf(m, h);
    }
    vm[j] = m;
  }
  for (int j = 0; j < 4; ++j) Xt[tn * 65 + to + 16 * j] = vm[j];
  __syncthreads();
  for (int s = 8; s > 0; s >>= 1) {
    if (tn < s)
      for (int j = 0; j < 4; ++j)
        Xt[tn * 65 + to + 16 * j] = fmaxf(Xt[tn * 65 + to + 16 * j], Xt[(tn + s) * 65 + to + 16 * j]);
    __syncthreads();
  }
  if (tn == 0)
    for (int j = 0; j < 4; ++j) {
      int o = o0 + to + 16 * j;
      partial[((long)b * NT + nb) * O + o] = Xt[0 * 65 + to + 16 * j];
    }
}

// fps role: 4 waves, dist[8] in VGPRs, swizzled LDS float4 coords
__device__ void fps_role(const float* __restrict__ xyz, int N, int M,
                         int* __restrict__ fpsIdx, float* __restrict__ node1,
                         int b, char* smem) {
  #pragma clang fp contract(off)
  float4* sp4 = (float4*)smem;               // 2048 float4, point n at slot (n&7)*256+(n>>3)
  int* fidx = (int*)(smem + 32768);          // 512 ints
  float* wvs = (float*)(smem + 34816);       // [2][4]
  int*   wis = (int*)(smem + 34848);         // [2][4]
  int tid = threadIdx.x;
  int lane = tid & 63, w = tid >> 6;
  const float* xb = xyz + (long)b * 3 * N;
  for (int n = tid; n < N; n += 256) {
    sp4[((n & 7) << 8) | (n >> 3)] = make_float4(xb[n], xb[N + n], xb[2 * N + n], 0.f);
  }
  __syncthreads();
  float dist[8];
  #pragma unroll
  for (int i = 0; i < 8; ++i) dist[i] = 1e10f;
  int base = tid * 8;
  int last = 0;
  for (int it = 0; it < M; ++it) {
    int p = it & 1;
    if (tid == 0) fidx[it] = last;
    float4 lp = sp4[((last & 7) << 8) | (last >> 3)];
    float best = -INFINITY; int bi = N;
    #pragma unroll
    for (int i = 0; i < 8; ++i) {
      float4 pt = sp4[(i << 8) | tid];
      float dx = pt.x - lp.x, dy = pt.y - lp.y, dz = pt.z - lp.z;
      float dx2 = dx * dx, dy2 = dy * dy, dz2 = dz * dz;
      float d = (dx2 + dy2) + dz2;
      float dn = dist[i];
      if (d < dn) dn = d;
      dist[i] = dn;
      if (dn > best) { best = dn; bi = base + i; }
    }
    float gmax = best;
    #pragma unroll
    for (int off = 32; off > 0; off >>= 1) {
      float ov = __shfl_xor(gmax, off);
      gmax = fmaxf(gmax, ov);
    }
    unsigned long long mm = __ballot(best == gmax);
    int srcLane = (int)(__ffsll((long long)mm) - 1);
    int wbi = __shfl(bi, srcLane);
    if (lane == 0) { wvs[p * 4 + w] = gmax; wis[p * 4 + w] = wbi; }
    __syncthreads();
    float bv = wvs[p * 4 + 0]; int bbi = wis[p * 4 + 0];
    #pragma unroll
    for (int ww = 1; ww < 4; ++ww) {
      float ov = wvs[p * 4 + ww]; int oi = wis[p * 4 + ww];
      if (ov > bv || (ov == bv && oi < bbi)) { bv = ov; bbi = oi; }
    }
    last = bbi;
  }
  for (int e = tid; e < M; e += 256) fpsIdx[(long)b * M + e] = fidx[e];
  for (int e = tid; e < 3 * M; e += 256) {
    int c = e / M, i = e % M;
    int src = fidx[i];
    float4 pt = sp4[((src & 7) << 8) | (src >> 3)];
    node1[(long)b * 3 * M + e] = (c == 0) ? pt.x : (c == 1) ? pt.y : pt.z;
  }
}

// ================= fused launch shells — __launch_bounds__(256, 4) caps VGPR<=128
// (R10's bare bounds let VGPR hit 144 -> 1 block/CU -> 4x knn slowdown; mega proved 84 suffices)

// stage1: blocks [0,8) fps | [8,4104) knn1 | [4104,4360) gemmPS1
__global__ void __launch_bounds__(256, 4) stage1_kernel(const float* __restrict__ x,
                                                        const float* __restrict__ W1,
                                                        float* Pt, float* St,
                                                        int* idxK, int* fpsI, float* node1) {
  __shared__ __align__(16) char smem[36864];
  int bid = blockIdx.x;
  if (bid < 8) {
    fps_role(x, 2048, 512, fpsI, node1, bid, smem);
  } else if (bid < 8 + 4096) {
    int u = bid - 8;
    knn_task(x, 3 * 2048, x, 3 * 2048, 3, 2048, 2048, 20, idxK, u / 512, (u % 512) * 4, smem);
  } else {
    int u = bid - 8 - 4096;
    gemmPS_task(x, 3 * 2048, 3, 2048, W1, 6, 64, Pt, St, u / 32, (u % 32) * 64, 0, smem);
  }
}

// stage2: [0,4096) knn2 | [4096,4352) gemmPS2 | [4352,5376) knn_agg -> idxAgg
__global__ void __launch_bounds__(256, 4) stage2_kernel(const float* __restrict__ x,
                                                        const float* __restrict__ xt1,
                                                        const float* __restrict__ node1,
                                                        const float* __restrict__ W2,
                                                        float* Pt, float* St,
                                                        int* idxK, int* idxAgg) {
  __shared__ __align__(16) char smem[36864];
  int bid = blockIdx.x;
  if (bid < 4096) {
    knn_task(xt1, (long)128 * 2048, xt1, (long)128 * 2048, 64, 2048, 2048, 20, idxK,
             bid / 512, (bid % 512) * 4, smem);
  } else if (bid < 4352) {
    int u = bid - 4096;
    gemmPS_task(xt1, (long)128 * 2048, 64, 2048, W2, 128, 64, Pt, St, u / 32, (u % 32) * 64, 0, smem);
  } else {
    int u = bid - 4352;
    knn_task(node1, 3 * 512, x, 3 * 2048, 3, 512, 2048, 20, idxAgg, u / 128, (u % 128) * 4, smem);
  }
}

// mid: [0,4096) colmaxA -> partA | [4096,6144) xmfill -> xm
__global__ void __launch_bounds__(256, 4) mid_kernel(const float* __restrict__ xt1,
                                                     const float* __restrict__ W2m,
                                                     const float* __restrict__ g2m, const float* __restrict__ b2m,
                                                     float* partA,
                                                     const int* __restrict__ fpsI, const int* __restrict__ idxAgg,
                                                     float* xm) {
  __shared__ __align__(16) char smem[36864];
  int bid = blockIdx.x;
  const int N = 2048, M = 512, K = 20;
  if (bid < 4096) {
    int b = bid / 512, rem = bid % 512;
    int nb = rem % 32, ob = rem / 32;
    colmax_task(xt1, (long)128 * N, 128, N, W2m, 128, 1024, g2m, b2m, partA, 32, b, nb * 64, ob * 64, nb, smem);
  } else {
    int u = bid - 4096;
    long t = (long)u * 256 + threadIdx.x;
    int i = (int)(t % M);
    int c = (int)((t / M) % 128);
    int b = (int)(t / ((long)128 * M));
    const float* xb = xt1 + (long)b * 128 * N + (long)c * N;
    float* xmB = xm + (long)b * 256 * M;
    xmB[(long)c * M + i] = xb[fpsI[(long)b * M + i]];
    const int* ip = idxAgg + ((long)b * M + i) * K;
    float best = -INFINITY;
    for (int kk = 0; kk < K; ++kk) best = fmaxf(best, xb[ip[kk]]);
    xmB[(long)(128 + c) * M + i] = best;
  }
}

// stage34: [0,1024) knn (C=256) | [1024,1280) gemmPS (O=256)
__global__ void __launch_bounds__(256, 4) stage34_kernel(const float* __restrict__ Xin, long xStrideB,
                                                         const float* __restrict__ W,
                                                         float* Pt, float* St, int* idxK) {
  __shared__ __align__(16) char smem[36864];
  int bid = blockIdx.x;
  if (bid < 1024) {
    knn_task(Xin, xStrideB, Xin, xStrideB, 256, 512, 512, 10, idxK, bid / 128, (bid % 128) * 4, smem);
  } else {
    int u = bid - 1024;
    gemmPS_task(Xin, xStrideB, 256, 512, W, 512, 256, Pt, St, u / 32, (u % 8) * 64, ((u / 8) % 4) * 64, smem);
  }
}

// ================= standalone kernels (unchanged from R8) =================

__global__ void ecfinish_kernel(const float* __restrict__ Pt, const float* __restrict__ St,
                                const int* __restrict__ idx, int k, int O, int Np,
                                const float* __restrict__ g, const float* __restrict__ bb,
                                float* __restrict__ outp, long oStrideB) {
  int b = blockIdx.y;
  int n = blockIdx.x * blockDim.y + threadIdx.y;
  int o = threadIdx.x;
  const float* PtB = Pt + (long)b * Np * O;
  const float* StB = St + (long)b * Np * O;
  const int* ip = idx + ((long)b * Np + n) * k;
  float mx = -INFINITY, mn = INFINITY;
  for (int kk = 0; kk < k; ++kk) {
    float v = PtB[(long)ip[kk] * O + o];
    mx = fmaxf(mx, v); mn = fminf(mn, v);
  }
  float ctrP = PtB[(long)n * O + o];
  float ctrS = StB[(long)n * O + o];
  float gs = g[o] * BN_SCALE;
  float m = (gs >= 0.f) ? mx : mn;
  float h = (ctrS - ctrP + m) * gs + bb[o];
  outp[(long)b * oStrideB + (long)o * Np + n] = h >= 0.f ? h : 0.2f * h;
}

__global__ void gemm_colmax_kernel(const float* __restrict__ X, int xStrideB, int C, int Np,
                                   const float* __restrict__ W, int ldw, int O,
                                   const float* __restrict__ g, const float* __restrict__ bb,
                                   float* __restrict__ partial) {
  __shared__ __align__(16) char smem[8320];
  int b = blockIdx.z;
  int nb = blockIdx.x, ob = blockIdx.y;
  colmax_task(X, xStrideB, C, Np, W, ldw, O, g, bb, partial, gridDim.x, b, nb * 64, ob * 64, nb, smem);
}

__global__ void head_kernel(const float* __restrict__ partA, int NTa,
                            const float* __restrict__ partB, int NTb,
                            const float* __restrict__ Wl1, const float* __restrict__ g6, const float* __restrict__ b6,
                            const float* __restrict__ Wl2, const float* __restrict__ bl2,
                            const float* __restrict__ g7, const float* __restrict__ b7,
                            const float* __restrict__ Wl3, const float* __restrict__ bl3,
                            float* __restrict__ logits) {
  __shared__ float v[2048];
  __shared__ float h1[512];
  __shared__ float h2[256];
  int b = blockIdx.x, tid = threadIdx.x;
  for (int o = tid; o < 1024; o += 256) {
    float m = -INFINITY;
    for (int t = 0; t < NTa; ++t) m = fmaxf(m, partA[((long)b * NTa + t) * 1024 + o]);
    v[o] = m;
    float m2 = -INFINITY;
    for (int t = 0; t < NTb; ++t) m2 = fmaxf(m2, partB[((long)b * NTb + t) * 1024 + o]);
    v[1024 + o] = m2;
  }
  __syncthreads();
  for (int o = tid; o < 512; o += 256) {
    const float* wr = Wl1 + (long)o * 2048;
    float s = 0.f;
    for (int c = 0; c < 2048; c += 4) {
      float4 w4 = *(const float4*)(wr + c);
      s = fmaf(w4.x, v[c], s); s = fmaf(w4.y, v[c + 1], s);
      s = fmaf(w4.z, v[c + 2], s); s = fmaf(w4.w, v[c + 3], s);
    }
    float h = s * (g6[o] * BN_SCALE) + b6[o];
    h1[o] = h >= 0.f ? h : 0.2f * h;
  }
  __syncthreads();
  for (int o = tid; o < 256; o += 256) {
    const float* wr = Wl2 + (long)o * 512;
    float s = 0.f;
    for (int c = 0; c < 512; c += 4) {
      float4 w4 = *(const float4*)(wr + c);
      s = fmaf(w4.x, h1[c], s); s = fmaf(w4.y, h1[c + 1], s);
      s = fmaf(w4.z, h1[c + 2], s); s = fmaf(w4.w, h1[c + 3], s);
    }
    s += bl2[o];
    float h = s * (g7[o] * BN_SCALE) + b7[o];
    h2[o] = h >= 0.f ? h : 0.2f * h;
  }
  __syncthreads();
  if (tid < 40) {
    const float* wr = Wl3 + (long)tid * 256;
    float s = 0.f;
    for (int c = 0; c < 256; ++c) s = fmaf(wr[c], h2[c], s);
    logits[(long)b * 40 + tid] = s + bl3[tid];
  }
}

extern "C" void kernel_launch(void* const* d_in, const int* in_sizes, int n_in,
                              void* d_out, int out_size, void* d_ws, size_t ws_size,
                              hipStream_t stream) {
  const float* x   = (const float*)d_in[0];
  const float* W1  = (const float*)d_in[1];
  const float* g1  = (const float*)d_in[2];
  const float* b1  = (const float*)d_in[3];
  const float* W2  = (const float*)d_in[4];
  const float* g2  = (const float*)d_in[5];
  const float* b2  = (const float*)d_in[6];
  const float* W2m = (const float*)d_in[7];
  const float* g2m = (const float*)d_in[8];
  const float* b2m = (const float*)d_in[9];
  const float* W3  = (const float*)d_in[10];
  const float* g3  = (const float*)d_in[11];
  const float* b3  = (const float*)d_in[12];
  const float* W4  = (const float*)d_in[13];
  const float* g4  = (const float*)d_in[14];
  const float* b4  = (const float*)d_in[15];
  const float* W5  = (const float*)d_in[16];
  const float* g5  = (const float*)d_in[17];
  const float* b5  = (const float*)d_in[18];
  const float* Wl1 = (const float*)d_in[19];
  const float* g6  = (const float*)d_in[20];
  const float* b6  = (const float*)d_in[21];
  const float* Wl2 = (const float*)d_in[22];
  const float* bl2 = (const float*)d_in[23];
  const float* g7  = (const float*)d_in[24];
  const float* b7  = (const float*)d_in[25];
  const float* Wl3 = (const float*)d_in[26];
  const float* bl3 = (const float*)d_in[27];
  float* outF = (float*)d_out;

  const int B = 8, N = 2048, K = 20, M = 512, K2 = 10;

  float* ws     = (float*)d_ws;
  float* xt1    = ws;                               // (B,128,N)
  float* xm     = xt1 + (size_t)B * 128 * N;        // (B,256,M)
  float* xc     = xm  + (size_t)B * 256 * M;        // (B,512,M)
  float* Pt     = xc  + (size_t)B * 512 * M;        // max(B*N*64, B*M*256)
  float* St     = Pt  + (size_t)B * N * 64;
  float* partA  = St  + (size_t)B * N * 64;         // (B,32,1024)
  float* partB  = partA + (size_t)B * 32 * 1024;    // (B,8,1024)
  int*   idxK   = (int*)(partB + (size_t)B * 8 * 1024);  // (B,N,K)
  int*   fpsI   = idxK + (size_t)B * N * K;         // (B,M)
  int*   idxAgg = fpsI + (size_t)B * M;             // (B,M,K)

  float* logits = outF;        // (B,40)
  float* node1  = outF + 320;  // (B,3,M)

  dim3 t256(256);

  // L1: fps + knn1 + gemmPS1 (all independent, read x)
  stage1_kernel<<<dim3(8 + 4096 + 256), t256, 0, stream>>>(x, W1, Pt, St, idxK, fpsI, node1);
  // ecf1 -> xt1 ch0..63
  ecfinish_kernel<<<dim3(N / 4, B), dim3(64, 4), 0, stream>>>(Pt, St, idxK, K, 64, N, g1, b1, xt1, (long)128 * N);
  // L2: knn2 + gemmPS2 + knn_agg (independent; knn_agg -> idxAgg)
  stage2_kernel<<<dim3(4096 + 256 + 1024), t256, 0, stream>>>(x, xt1, node1, W2, Pt, St, idxK, idxAgg);
  // ecf2 -> xt1 ch64..127
  ecfinish_kernel<<<dim3(N / 4, B), dim3(64, 4), 0, stream>>>(Pt, St, idxK, K, 64, N, g2, b2,
                                                              xt1 + (size_t)64 * N, (long)128 * N);
  // L3: colmaxA + xmfill (independent)
  mid_kernel<<<dim3(4096 + 2048), t256, 0, stream>>>(xt1, W2m, g2m, b2m, partA, fpsI, idxAgg, xm);
  // L4: knn3 + gemmPS3
  stage34_kernel<<<dim3(1024 + 256), t256, 0, stream>>>(xm, (long)256 * M, W3, Pt, St, idxK);
  // ecf3 -> xc ch0..255
  ecfinish_kernel<<<dim3(M, B), dim3(256, 1), 0, stream>>>(Pt, St, idxK, K2, 256, M, g3, b3, xc, (long)512 * M);
  // L5: knn4 + gemmPS4
  stage34_kernel<<<dim3(1024 + 256), t256, 0, stream>>>(xc, (long)512 * M, W4, Pt, St, idxK);
  // ecf4 -> xc ch256..511
  ecfinish_kernel<<<dim3(M, B), dim3(256, 1), 0, stream>>>(Pt, St, idxK, K2, 256, M, g4, b4,
                                                           xc + (size_t)256 * M, (long)512 * M);
  // colmaxB -> partB
  gemm_colmax_kernel<<<dim3(M / 64, 1024 / 64, B), t256, 0, stream>>>(xc, 512 * M, 512, M, W5, 512, 1024,
                                                                      g5, b5, partB);
  // head (fused colmax_finish + MLP)
  head_kernel<<<dim3(B), t256, 0, stream>>>(partA, 32, partB, 8,
                                            Wl1, g6, b6, Wl2, bl2, g7, b7, Wl3, bl3, logits);
}

// Round 13
// 4273.764 us; speedup vs baseline: 1.1926x; 1.0119x over previous
//
#include <hip/hip_runtime.h>

#define BN_SCALE 0.9999950000374997f  // 1/sqrt(1+1e-5)

// ================= device task functions (verified R8/R9/R11) =================

// knn task: 4 queries; candidate sq-norm folded; |q|^2 row-shift dropped (top_k invariant)
__device__ void knn_task(const float* __restrict__ Q, long qStrideB,
                         const float* __restrict__ Xc, long cStrideB,
                         int C, int Mq, int N, int k, int* __restrict__ idxOut,
                         int b, int q0, char* smem) {
  float* qv = (float*)smem;             // [4][256]
  float* negd = (float*)(smem + 4096);  // [4][2048]
  int tid = threadIdx.x;
  for (int e = tid; e < 4 * C; e += 256) {
    int qq = e / C, c = e % C;
    qv[qq * 256 + c] = Q[(long)b * qStrideB + (long)c * Mq + (q0 + qq)];
  }
  __syncthreads();
  const float* cb = Xc + (long)b * cStrideB;
  for (int m = tid; m < N; m += 256) {
    float d0 = 0.f, d1 = 0.f, d2 = 0.f, d3 = 0.f, sq = 0.f;
    for (int c = 0; c < C; ++c) {
      float xv = cb[(long)c * N + m];
      d0 = fmaf(qv[0 * 256 + c], xv, d0);
      d1 = fmaf(qv[1 * 256 + c], xv, d1);
      d2 = fmaf(qv[2 * 256 + c], xv, d2);
      d3 = fmaf(qv[3 * 256 + c], xv, d3);
      sq = fmaf(xv, xv, sq);
    }
    negd[0 * 2048 + m] = 2.f * d0 - sq;
    negd[1 * 2048 + m] = 2.f * d1 - sq;
    negd[2 * 2048 + m] = 2.f * d2 - sq;
    negd[3 * 2048 + m] = 2.f * d3 - sq;
  }
  __syncthreads();
  int lane = tid & 63, w = tid >> 6;
  float* row = negd + w * 2048;
  int* outp = idxOut + ((long)b * Mq + (q0 + w)) * k;
  for (int kk = 0; kk < k; ++kk) {
    float best = -INFINITY; int bi = N;
    for (int m = lane; m < N; m += 64) {
      float vv = row[m];
      if (vv > best) { best = vv; bi = m; }
    }
    for (int off = 32; off > 0; off >>= 1) {
      float ov = __shfl_xor(best, off);
      int   oi = __shfl_xor(bi, off);
      if (ov > best || (ov == best && oi < bi)) { best = ov; bi = oi; }
    }
    if (lane == (bi & 63)) row[bi] = -INFINITY;
    if (lane == 0) outp[kk] = bi;
  }
}

// gemmPS task: both halves of edge-conv weight in one pass
__device__ void gemmPS_task(const float* __restrict__ X, long xStrideB, int C, int Np,
                            const float* __restrict__ W, int ldw, int O,
                            float* __restrict__ PtT, float* __restrict__ StT,
                            int b, int n0, int o0, char* smem) {
  float* Wp = (float*)smem;
  float* Ws = (float*)(smem + 4160);
  float* Xt = (float*)(smem + 8320);
  int tid = threadIdx.x;
  int to = tid % 16, tn = tid / 16;
  float accP[4][4] = {}, accS[4][4] = {};
  for (int c0 = 0; c0 < C; c0 += 16) {
    for (int e = tid; e < 16 * 64; e += 256) {
      int oo = e / 16, kk = e % 16;
      int c = c0 + kk, o = o0 + oo;
      bool ok = (c < C && o < O);
      Wp[kk * 65 + oo] = ok ? W[(long)o * ldw + c] : 0.f;
      Ws[kk * 65 + oo] = ok ? W[(long)o * ldw + C + c] : 0.f;
    }
    for (int e = tid; e < 16 * 64; e += 256) {
      int kk = e / 64, nn = e % 64;
      int c = c0 + kk, n = n0 + nn;
      Xt[kk * 65 + nn] = (c < C && n < Np) ? X[(long)b * xStrideB + (long)c * Np + n] : 0.f;
    }
    __syncthreads();
    for (int kk = 0; kk < 16; ++kk) {
      float xv[4], wp[4], ws[4];
      for (int i = 0; i < 4; ++i) xv[i] = Xt[kk * 65 + tn + 16 * i];
      for (int j = 0; j < 4; ++j) { wp[j] = Wp[kk * 65 + to + 16 * j]; ws[j] = Ws[kk * 65 + to + 16 * j]; }
      for (int i = 0; i < 4; ++i)
        for (int j = 0; j < 4; ++j) {
          accP[i][j] = fmaf(xv[i], wp[j], accP[i][j]);
          accS[i][j] = fmaf(xv[i], ws[j], accS[i][j]);
        }
    }
    __syncthreads();
  }
  for (int i = 0; i < 4; ++i) {
    int n = n0 + tn + 16 * i;
    if (n >= Np) continue;
    for (int j = 0; j < 4; ++j) {
      int o = o0 + to + 16 * j;
      if (o < O) {
        long off = ((long)b * Np + n) * O + o;
        PtT[off] = accP[i][j];
        StT[off] = accS[i][j];
      }
    }
  }
}

// colmax task (one 64x64 tile), partial[b][nb][o]
__device__ void colmax_task(const float* __restrict__ X, long xStrideB, int C, int Np,
                            const float* __restrict__ W, int ldw, int O,
                            const float* __restrict__ g, const float* __restrict__ bb,
                            float* __restrict__ partial, int NT,
                            int b, int n0, int o0, int nb, char* smem) {
  float* Wt = (float*)smem;
  float* Xt = (float*)(smem + 4160);
  int tid = threadIdx.x;
  int to = tid % 16, tn = tid / 16;
  float acc[4][4] = {};
  for (int c0 = 0; c0 < C; c0 += 16) {
    for (int e = tid; e < 16 * 64; e += 256) {
      int oo = e / 16, kk = e % 16;
      int c = c0 + kk, o = o0 + oo;
      Wt[kk * 65 + oo] = (c < C && o < O) ? W[(long)o * ldw + c] : 0.f;
    }
    for (int e = tid; e < 16 * 64; e += 256) {
      int kk = e / 64, nn = e % 64;
      int c = c0 + kk, n = n0 + nn;
      Xt[kk * 65 + nn] = (c < C && n < Np) ? X[(long)b * xStrideB + (long)c * Np + n] : 0.f;
    }
    __syncthreads();
    for (int kk = 0; kk < 16; ++kk) {
      float xv[4], wv[4];
      for (int i = 0; i < 4; ++i) xv[i] = Xt[kk * 65 + tn + 16 * i];
      for (int j = 0; j < 4; ++j) wv[j] = Wt[kk * 65 + to + 16 * j];
      for (int i = 0; i < 4; ++i)
        for (int j = 0; j < 4; ++j) acc[i][j] = fmaf(xv[i], wv[j], acc[i][j]);
    }
    __syncthreads();
  }
  float vm[4];
  for (int j = 0; j < 4; ++j) {
    int o = o0 + to + 16 * j;
    float gs = g[o] * BN_SCALE, bo = bb[o];
    float m = -INFINITY;
    for (int i = 0; i < 4; ++i) {
      float h = acc[i][j] * gs + bo;
      h = h >= 0.f ? h : 0.2f * h;
      m = fmaxf(m, h);
    }
    vm[j] = m;
  }
  for (int j = 0; j < 4; ++j) Xt[tn * 65 + to + 16 * j] = vm[j];
  __syncthreads();
  for (int s = 8; s > 0; s >>= 1) {
    if (tn < s)
      for (int j = 0; j < 4; ++j)
        Xt[tn * 65 + to + 16 * j] = fmaxf(Xt[tn * 65 + to + 16 * j], Xt[(tn + s) * 65 + to + 16 * j]);
    __syncthreads();
  }
  if (tn == 0)
    for (int j = 0; j < 4; ++j) {
      int o = o0 + to + 16 * j;
      partial[((long)b * NT + nb) * O + o] = Xt[0 * 65 + to + 16 * j];
    }
}

// fps role: 4 waves, dist[8] in VGPRs, swizzled LDS float4 coords
__device__ void fps_role(const float* __restrict__ xyz, int N, int M,
                         int* __restrict__ fpsIdx, float* __restrict__ node1,
                         int b, char* smem) {
  #pragma clang fp contract(off)
  float4* sp4 = (float4*)smem;               // 2048 float4, point n at slot (n&7)*256+(n>>3)
  int* fidx = (int*)(smem + 32768);          // 512 ints
  float* wvs = (float*)(smem + 34816);       // [2][4]
  int*   wis = (int*)(smem + 34848);         // [2][4]
  int tid = threadIdx.x;
  int lane = tid & 63, w = tid >> 6;
  const float* xb = xyz + (long)b * 3 * N;
  for (int n = tid; n < N; n += 256) {
    sp4[((n & 7) << 8) | (n >> 3)] = make_float4(xb[n], xb[N + n], xb[2 * N + n], 0.f);
  }
  __syncthreads();
  float dist[8];
  #pragma unroll
  for (int i = 0; i < 8; ++i) dist[i] = 1e10f;
  int base = tid * 8;
  int last = 0;
  for (int it = 0; it < M; ++it) {
    int p = it & 1;
    if (tid == 0) fidx[it] = last;
    float4 lp = sp4[((last & 7) << 8) | (last >> 3)];
    float best = -INFINITY; int bi = N;
    #pragma unroll
    for (int i = 0; i < 8; ++i) {
      float4 pt = sp4[(i << 8) | tid];
      float dx = pt.x - lp.x, dy = pt.y - lp.y, dz = pt.z - lp.z;
      float dx2 = dx * dx, dy2 = dy * dy, dz2 = dz * dz;
      float d = (dx2 + dy2) + dz2;
      float dn = dist[i];
      if (d < dn) dn = d;
      dist[i] = dn;
      if (dn > best) { best = dn; bi = base + i; }
    }
    float gmax = best;
    #pragma unroll
    for (int off = 32; off > 0; off >>= 1) {
      float ov = __shfl_xor(gmax, off);
      gmax = fmaxf(gmax, ov);
    }
    unsigned long long mm = __ballot(best == gmax);
    int srcLane = (int)(__ffsll((long long)mm) - 1);
    int wbi = __shfl(bi, srcLane);
    if (lane == 0) { wvs[p * 4 + w] = gmax; wis[p * 4 + w] = wbi; }
    __syncthreads();
    float bv = wvs[p * 4 + 0]; int bbi = wis[p * 4 + 0];
    #pragma unroll
    for (int ww = 1; ww < 4; ++ww) {
      float ov = wvs[p * 4 + ww]; int oi = wis[p * 4 + ww];
      if (ov > bv || (ov == bv && oi < bbi)) { bv = ov; bbi = oi; }
    }
    last = bbi;
  }
  for (int e = tid; e < M; e += 256) fpsIdx[(long)b * M + e] = fidx[e];
  for (int e = tid; e < 3 * M; e += 256) {
    int c = e / M, i = e % M;
    int src = fidx[i];
    float4 pt = sp4[((src & 7) << 8) | (src >> 3)];
    node1[(long)b * 3 * M + e] = (c == 0) ? pt.x : (c == 1) ? pt.y : pt.z;
  }
}

// ================= fused launch shells — (256,4) caps VGPR<=128 (R11: VGPR=64 measured).
// ALL task maps use batch = raw_bid % 8: round-robin dispatch puts one batch per XCD,
// so each XCD's L2 holds exactly its batch's slab (R11: FETCH 2.7GB from cross-XCD thrash).

// stage1: blocks [0,8) fps | [8,4104) knn1 | [4104,4360) gemmPS1  (all offsets % 8 == 0)
__global__ void __launch_bounds__(256, 4) stage1_kernel(const float* __restrict__ x,
                                                        const float* __restrict__ W1,
                                                        float* Pt, float* St,
                                                        int* idxK, int* fpsI, float* node1) {
  __shared__ __align__(16) char smem[36864];
  int bid = blockIdx.x;
  if (bid < 8) {
    fps_role(x, 2048, 512, fpsI, node1, bid, smem);
  } else if (bid < 8 + 4096) {
    int u = bid - 8;
    knn_task(x, 3 * 2048, x, 3 * 2048, 3, 2048, 2048, 20, idxK, u % 8, (u / 8) * 4, smem);
  } else {
    int u = bid - 8 - 4096;
    gemmPS_task(x, 3 * 2048, 3, 2048, W1, 6, 64, Pt, St, u % 8, (u / 8) * 64, 0, smem);
  }
}

// stage2: [0,4096) knn2 | [4096,4352) gemmPS2 | [4352,5376) knn_agg -> idxAgg
__global__ void __launch_bounds__(256, 4) stage2_kernel(const float* __restrict__ x,
                                                        const float* __restrict__ xt1,
                                                        const float* __restrict__ node1,
                                                        const float* __restrict__ W2,
                                                        float* Pt, float* St,
                                                        int* idxK, int* idxAgg) {
  __shared__ __align__(16) char smem[36864];
  int bid = blockIdx.x;
  if (bid < 4096) {
    knn_task(xt1, (long)128 * 2048, xt1, (long)128 * 2048, 64, 2048, 2048, 20, idxK,
             bid % 8, (bid / 8) * 4, smem);
  } else if (bid < 4352) {
    int u = bid - 4096;
    gemmPS_task(xt1, (long)128 * 2048, 64, 2048, W2, 128, 64, Pt, St, u % 8, (u / 8) * 64, 0, smem);
  } else {
    int u = bid - 4352;
    knn_task(node1, 3 * 512, x, 3 * 2048, 3, 512, 2048, 20, idxAgg, u % 8, (u / 8) * 4, smem);
  }
}

// mid: [0,4096) colmaxA -> partA | [4096,6144) xmfill -> xm
__global__ void __launch_bounds__(256, 4) mid_kernel(const float* __restrict__ xt1,
                                                     const float* __restrict__ W2m,
                                                     const float* __restrict__ g2m, const float* __restrict__ b2m,
                                                     float* partA,
                                                     const int* __restrict__ fpsI, const int* __restrict__ idxAgg,
                                                     float* xm) {
  __shared__ __align__(16) char smem[36864];
  int bid = blockIdx.x;
  const int N = 2048, M = 512, K = 20;
  if (bid < 4096) {
    int b = bid % 8, rem = bid / 8;      // rem 0..511
    int nb = rem % 32, ob = rem / 32;
    colmax_task(xt1, (long)128 * N, 128, N, W2m, 128, 1024, g2m, b2m, partA, 32, b, nb * 64, ob * 64, nb, smem);
  } else {
    int u = bid - 4096;                  // 0..2047
    int b = u % 8, inner = u / 8;        // inner 0..255
    long t = (long)inner * 256 + threadIdx.x;
    int i = (int)(t % M);
    int c = (int)(t / M);                // 0..127
    const float* xb = xt1 + (long)b * 128 * N + (long)c * N;
    float* xmB = xm + (long)b * 256 * M;
    xmB[(long)c * M + i] = xb[fpsI[(long)b * M + i]];
    const int* ip = idxAgg + ((long)b * M + i) * K;
    float best = -INFINITY;
    for (int kk = 0; kk < K; ++kk) best = fmaxf(best, xb[ip[kk]]);
    xmB[(long)(128 + c) * M + i] = best;
  }
}

// stage34: [0,1024) knn (C=256) | [1024,1280) gemmPS (O=256)
__global__ void __launch_bounds__(256, 4) stage34_kernel(const float* __restrict__ Xin, long xStrideB,
                                                         const float* __restrict__ W,
                                                         float* Pt, float* St, int* idxK) {
  __shared__ __align__(16) char smem[36864];
  int bid = blockIdx.x;
  if (bid < 1024) {
    knn_task(Xin, xStrideB, Xin, xStrideB, 256, 512, 512, 10, idxK, bid % 8, (bid / 8) * 4, smem);
  } else {
    int u = bid - 1024;                  // 0..255
    int b = u % 8, rem = u / 8;          // rem 0..31
    gemmPS_task(Xin, xStrideB, 256, 512, W, 512, 256, Pt, St, b, (rem % 8) * 64, (rem / 8) * 64, smem);
  }
}

// ================= standalone kernels (1D grids, batch = bid % 8) =================

__global__ void ecfinish_kernel(const float* __restrict__ Pt, const float* __restrict__ St,
                                const int* __restrict__ idx, int k, int O, int Np,
                                const float* __restrict__ g, const float* __restrict__ bb,
                                float* __restrict__ outp, long oStrideB) {
  int b = blockIdx.x % 8;
  int n = (blockIdx.x / 8) * blockDim.y + threadIdx.y;
  int o = threadIdx.x;
  const float* PtB = Pt + (long)b * Np * O;
  const float* StB = St + (long)b * Np * O;
  const int* ip = idx + ((long)b * Np + n) * k;
  float mx = -INFINITY, mn = INFINITY;
  for (int kk = 0; kk < k; ++kk) {
    float v = PtB[(long)ip[kk] * O + o];
    mx = fmaxf(mx, v); mn = fminf(mn, v);
  }
  float ctrP = PtB[(long)n * O + o];
  float ctrS = StB[(long)n * O + o];
  float gs = g[o] * BN_SCALE;
  float m = (gs >= 0.f) ? mx : mn;
  float h = (ctrS - ctrP + m) * gs + bb[o];
  outp[(long)b * oStrideB + (long)o * Np + n] = h >= 0.f ? h : 0.2f * h;
}

__global__ void gemm_colmax_kernel(const float* __restrict__ X, int xStrideB, int C, int Np,
                                   const float* __restrict__ W, int ldw, int O,
                                   const float* __restrict__ g, const float* __restrict__ bb,
                                   float* __restrict__ partial, int NT) {
  __shared__ __align__(16) char smem[8320];
  int b = blockIdx.x % 8, rem = blockIdx.x / 8;
  int nb = rem % NT, ob = rem / NT;
  colmax_task(X, xStrideB, C, Np, W, ldw, O, g, bb, partial, NT, b, nb * 64, ob * 64, nb, smem);
}

__global__ void head_kernel(const float* __restrict__ partA, int NTa,
                            const float* __restrict__ partB, int NTb,
                            const float* __restrict__ Wl1, const float* __restrict__ g6, const float* __restrict__ b6,
                            const float* __restrict__ Wl2, const float* __restrict__ bl2,
                            const float* __restrict__ g7, const float* __restrict__ b7,
                            const float* __restrict__ Wl3, const float* __restrict__ bl3,
                            float* __restrict__ logits) {
  __shared__ float v[2048];
  __shared__ float h1[512];
  __shared__ float h2[256];
  int b = blockIdx.x, tid = threadIdx.x;
  for (int o = tid; o < 1024; o += 256) {
    float m = -INFINITY;
    for (int t = 0; t < NTa; ++t) m = fmaxf(m, partA[((long)b * NTa + t) * 1024 + o]);
    v[o] = m;
    float m2 = -INFINITY;
    for (int t = 0; t < NTb; ++t) m2 = fmaxf(m2, partB[((long)b * NTb + t) * 1024 + o]);
    v[1024 + o] = m2;
  }
  __syncthreads();
  for (int o = tid; o < 512; o += 256) {
    const float* wr = Wl1 + (long)o * 2048;
    float s = 0.f;
    for (int c = 0; c < 2048; c += 4) {
      float4 w4 = *(const float4*)(wr + c);
      s = fmaf(w4.x, v[c], s); s = fmaf(w4.y, v[c + 1], s);
      s = fmaf(w4.z, v[c + 2], s); s = fmaf(w4.w, v[c + 3], s);
    }
    float h = s * (g6[o] * BN_SCALE) + b6[o];
    h1[o] = h >= 0.f ? h : 0.2f * h;
  }
  __syncthreads();
  for (int o = tid; o < 256; o += 256) {
    const float* wr = Wl2 + (long)o * 512;
    float s = 0.f;
    for (int c = 0; c < 512; c += 4) {
      float4 w4 = *(const float4*)(wr + c);
      s = fmaf(w4.x, h1[c], s); s = fmaf(w4.y, h1[c + 1], s);
      s = fmaf(w4.z, h1[c + 2], s); s = fmaf(w4.w, h1[c + 3], s);
    }
    s += bl2[o];
    float h = s * (g7[o] * BN_SCALE) + b7[o];
    h2[o] = h >= 0.f ? h : 0.2f * h;
  }
  __syncthreads();
  if (tid < 40) {
    const float* wr = Wl3 + (long)tid * 256;
    float s = 0.f;
    for (int c = 0; c < 256; ++c) s = fmaf(wr[c], h2[c], s);
    logits[(long)b * 40 + tid] = s + bl3[tid];
  }
}

extern "C" void kernel_launch(void* const* d_in, const int* in_sizes, int n_in,
                              void* d_out, int out_size, void* d_ws, size_t ws_size,
                              hipStream_t stream) {
  const float* x   = (const float*)d_in[0];
  const float* W1  = (const float*)d_in[1];
  const float* g1  = (const float*)d_in[2];
  const float* b1  = (const float*)d_in[3];
  const float* W2  = (const float*)d_in[4];
  const float* g2  = (const float*)d_in[5];
  const float* b2  = (const float*)d_in[6];
  const float* W2m = (const float*)d_in[7];
  const float* g2m = (const float*)d_in[8];
  const float* b2m = (const float*)d_in[9];
  const float* W3  = (const float*)d_in[10];
  const float* g3  = (const float*)d_in[11];
  const float* b3  = (const float*)d_in[12];
  const float* W4  = (const float*)d_in[13];
  const float* g4  = (const float*)d_in[14];
  const float* b4  = (const float*)d_in[15];
  const float* W5  = (const float*)d_in[16];
  const float* g5  = (const float*)d_in[17];
  const float* b5  = (const float*)d_in[18];
  const float* Wl1 = (const float*)d_in[19];
  const float* g6  = (const float*)d_in[20];
  const float* b6  = (const float*)d_in[21];
  const float* Wl2 = (const float*)d_in[22];
  const float* bl2 = (const float*)d_in[23];
  const float* g7  = (const float*)d_in[24];
  const float* b7  = (const float*)d_in[25];
  const float* Wl3 = (const float*)d_in[26];
  const float* bl3 = (const float*)d_in[27];
  float* outF = (float*)d_out;

  const int B = 8, N = 2048, K = 20, M = 512, K2 = 10;

  float* ws     = (float*)d_ws;
  float* xt1    = ws;                               // (B,128,N)
  float* xm     = xt1 + (size_t)B * 128 * N;        // (B,256,M)
  float* xc     = xm  + (size_t)B * 256 * M;        // (B,512,M)
  float* Pt     = xc  + (size_t)B * 512 * M;        // max(B*N*64, B*M*256)
  float* St     = Pt  + (size_t)B * N * 64;
  float* partA  = St  + (size_t)B * N * 64;         // (B,32,1024)
  float* partB  = partA + (size_t)B * 32 * 1024;    // (B,8,1024)
  int*   idxK   = (int*)(partB + (size_t)B * 8 * 1024);  // (B,N,K)
  int*   fpsI   = idxK + (size_t)B * N * K;         // (B,M)
  int*   idxAgg = fpsI + (size_t)B * M;             // (B,M,K)

  float* logits = outF;        // (B,40)
  float* node1  = outF + 320;  // (B,3,M)

  dim3 t256(256);

  // L1: fps + knn1 + gemmPS1 (all independent, read x)
  stage1_kernel<<<dim3(8 + 4096 + 256), t256, 0, stream>>>(x, W1, Pt, St, idxK, fpsI, node1);
  // ecf1 -> xt1 ch0..63
  ecfinish_kernel<<<dim3(4096), dim3(64, 4), 0, stream>>>(Pt, St, idxK, K, 64, N, g1, b1, xt1, (long)128 * N);
  // L2: knn2 + gemmPS2 + knn_agg (independent; knn_agg -> idxAgg)
  stage2_kernel<<<dim3(4096 + 256 + 1024), t256, 0, stream>>>(x, xt1, node1, W2, Pt, St, idxK, idxAgg);
  // ecf2 -> xt1 ch64..127
  ecfinish_kernel<<<dim3(4096), dim3(64, 4), 0, stream>>>(Pt, St, idxK, K, 64, N, g2, b2,
                                                          xt1 + (size_t)64 * N, (long)128 * N);
  // L3: colmaxA + xmfill (independent)
  mid_kernel<<<dim3(4096 + 2048), t256, 0, stream>>>(xt1, W2m, g2m, b2m, partA, fpsI, idxAgg, xm);
  // L4: knn3 + gemmPS3
  stage34_kernel<<<dim3(1024 + 256), t256, 0, stream>>>(xm, (long)256 * M, W3, Pt, St, idxK);
  // ecf3 -> xc ch0..255
  ecfinish_kernel<<<dim3(4096), dim3(256, 1), 0, stream>>>(Pt, St, idxK, K2, 256, M, g3, b3, xc, (long)512 * M);
  // L5: knn4 + gemmPS4
  stage34_kernel<<<dim3(1024 + 256), t256, 0, stream>>>(xc, (long)512 * M, W4, Pt, St, idxK);
  // ecf4 -> xc ch256..511
  ecfinish_kernel<<<dim3(4096), dim3(256, 1), 0, stream>>>(Pt, St, idxK, K2, 256, M, g4, b4,
                                                           xc + (size_t)256 * M, (long)512 * M);
  // colmaxB -> partB (1024 blocks: b=bid%8, NT=8)
  gemm_colmax_kernel<<<dim3(1024), t256, 0, stream>>>(xc, 512 * M, 512, M, W5, 512, 1024,
                                                      g5, b5, partB, 8);
  // head (fused colmax_finish + MLP)
  head_kernel<<<dim3(B), t256, 0, stream>>>(partA, 32, partB, 8,
                                            Wl1, g6, b6, Wl2, bl2, g7, b7, Wl3, bl3, logits);
}

// Round 14
// 2999.858 us; speedup vs baseline: 1.6990x; 1.4247x over previous
//
#include <hip/hip_runtime.h>

#define BN_SCALE 0.9999950000374997f  // 1/sqrt(1+1e-5)

// ---------------- knn16: 16 queries/block (4x less slab re-read than Q=4).
// Scores: 2*dot - |x_m|^2 (per-row -|q|^2 dropped; top_k invariant — validated R7+).
// Extraction per query identical to validated Q=4 version (same tie-breaks).
template<int MAXN, int MAXC>
__global__ void knn16_kernel(const float* __restrict__ Q, long qStrideB,
                             const float* __restrict__ Xc, long cStrideB,
                             int C, int Mq, int k, int* __restrict__ idxOut) {
  __shared__ float qv[16 * MAXC];
  __shared__ float negd[16 * MAXN];
  int b = blockIdx.y, q0 = blockIdx.x * 16, tid = threadIdx.x;
  for (int e = tid; e < 16 * C; e += 256) {
    int qq = e / C, c = e % C;
    qv[qq * C + c] = Q[(long)b * qStrideB + (long)c * Mq + (q0 + qq)];
  }
  __syncthreads();
  const float* cb = Xc + (long)b * cStrideB;
  constexpr int UN = (MAXN >= 2048) ? 4 : 2;     // m-unroll; N == MAXN for all call sites
  constexpr int STEP = 256 * UN;
  for (int m0 = tid; m0 < MAXN; m0 += STEP) {
    float d[16][UN];
    float sq[UN];
    #pragma unroll
    for (int i = 0; i < 16; ++i)
      #pragma unroll
      for (int j = 0; j < UN; ++j) d[i][j] = 0.f;
    #pragma unroll
    for (int j = 0; j < UN; ++j) sq[j] = 0.f;
    for (int c = 0; c < C; ++c) {
      float xv[UN];
      #pragma unroll
      for (int j = 0; j < UN; ++j) xv[j] = cb[(long)c * MAXN + m0 + j * 256];
      #pragma unroll
      for (int j = 0; j < UN; ++j) sq[j] = fmaf(xv[j], xv[j], sq[j]);
      #pragma unroll
      for (int i = 0; i < 16; ++i) {
        float qvv = qv[i * C + c];
        #pragma unroll
        for (int j = 0; j < UN; ++j) d[i][j] = fmaf(qvv, xv[j], d[i][j]);
      }
    }
    #pragma unroll
    for (int i = 0; i < 16; ++i)
      #pragma unroll
      for (int j = 0; j < UN; ++j)
        negd[i * MAXN + m0 + j * 256] = 2.f * d[i][j] - sq[j];
  }
  __syncthreads();
  int lane = tid & 63, w = tid >> 6;
  for (int qq = w * 4; qq < w * 4 + 4; ++qq) {
    float* row = negd + qq * MAXN;
    int* outp = idxOut + ((long)b * Mq + (q0 + qq)) * k;
    for (int kk = 0; kk < k; ++kk) {
      float best = -INFINITY; int bi = MAXN;
      for (int m = lane; m < MAXN; m += 64) {
        float vv = row[m];
        if (vv > best) { best = vv; bi = m; }   // ascending -> first max kept
      }
      for (int off = 32; off > 0; off >>= 1) {
        float ov = __shfl_xor(best, off);
        int   oi = __shfl_xor(bi, off);
        if (ov > best || (ov == best && oi < bi)) { best = ov; bi = oi; }
      }
      if (lane == (bi & 63)) row[bi] = -INFINITY;
      if (lane == 0) outp[kk] = bi;
    }
  }
}

// ---------------- gemmPS (R8-proven): both halves of edge-conv weight ----------------
__global__ void gemmPS_kernel(const float* __restrict__ X, int xStrideB, int C, int Np,
                              const float* __restrict__ W, int ldw, int O,
                              float* __restrict__ PtT, float* __restrict__ StT) {
  __shared__ float Wp[16][65];
  __shared__ float Ws[16][65];
  __shared__ float Xt[16][65];
  int b = blockIdx.z;
  int n0 = blockIdx.x * 64, o0 = blockIdx.y * 64;
  int tid = threadIdx.x;
  int to = tid % 16, tn = tid / 16;
  float accP[4][4] = {}, accS[4][4] = {};
  for (int c0 = 0; c0 < C; c0 += 16) {
    for (int e = tid; e < 16 * 64; e += 256) {
      int oo = e / 16, kk = e % 16;
      int c = c0 + kk, o = o0 + oo;
      bool ok = (c < C && o < O);
      Wp[kk][oo] = ok ? W[(long)o * ldw + c] : 0.f;
      Ws[kk][oo] = ok ? W[(long)o * ldw + C + c] : 0.f;
    }
    for (int e = tid; e < 16 * 64; e += 256) {
      int kk = e / 64, nn = e % 64;
      int c = c0 + kk, n = n0 + nn;
      Xt[kk][nn] = (c < C && n < Np) ? X[(long)b * xStrideB + (long)c * Np + n] : 0.f;
    }
    __syncthreads();
    for (int kk = 0; kk < 16; ++kk) {
      float xv[4], wp[4], ws[4];
      for (int i = 0; i < 4; ++i) xv[i] = Xt[kk][tn + 16 * i];
      for (int j = 0; j < 4; ++j) { wp[j] = Wp[kk][to + 16 * j]; ws[j] = Ws[kk][to + 16 * j]; }
      for (int i = 0; i < 4; ++i)
        for (int j = 0; j < 4; ++j) {
          accP[i][j] = fmaf(xv[i], wp[j], accP[i][j]);
          accS[i][j] = fmaf(xv[i], ws[j], accS[i][j]);
        }
    }
    __syncthreads();
  }
  for (int i = 0; i < 4; ++i) {
    int n = n0 + tn + 16 * i;
    if (n >= Np) continue;
    for (int j = 0; j < 4; ++j) {
      int o = o0 + to + 16 * j;
      if (o < O) {
        long off = ((long)b * Np + n) * O + o;
        PtT[off] = accP[i][j];
        StT[off] = accS[i][j];
      }
    }
  }
}

// ---------------- ecfinish (R8-proven) ----------------
__global__ void ecfinish_kernel(const float* __restrict__ Pt, const float* __restrict__ St,
                                const int* __restrict__ idx, int k, int O, int Np,
                                const float* __restrict__ g, const float* __restrict__ bb,
                                float* __restrict__ outp, long oStrideB) {
  int b = blockIdx.y;
  int n = blockIdx.x * blockDim.y + threadIdx.y;
  int o = threadIdx.x;
  const float* PtB = Pt + (long)b * Np * O;
  const float* StB = St + (long)b * Np * O;
  const int* ip = idx + ((long)b * Np + n) * k;
  float mx = -INFINITY, mn = INFINITY;
  for (int kk = 0; kk < k; ++kk) {
    float v = PtB[(long)ip[kk] * O + o];
    mx = fmaxf(mx, v); mn = fminf(mn, v);
  }
  float ctrP = PtB[(long)n * O + o];
  float ctrS = StB[(long)n * O + o];
  float gs = g[o] * BN_SCALE;
  float m = (gs >= 0.f) ? mx : mn;
  float h = (ctrS - ctrP + m) * gs + bb[o];
  outp[(long)b * oStrideB + (long)o * Np + n] = h >= 0.f ? h : 0.2f * h;
}

// ---------------- gemm_colmax (R8-proven) ----------------
__global__ void gemm_colmax_kernel(const float* __restrict__ X, int xStrideB, int C, int Np,
                                   const float* __restrict__ W, int ldw, int O,
                                   const float* __restrict__ g, const float* __restrict__ bb,
                                   float* __restrict__ partial) {
  __shared__ float Wt[16][65];
  __shared__ float Xt[16][65];
  int b = blockIdx.z;
  int n0 = blockIdx.x * 64, o0 = blockIdx.y * 64;
  int tid = threadIdx.x;
  int to = tid % 16, tn = tid / 16;
  float acc[4][4] = {};
  for (int c0 = 0; c0 < C; c0 += 16) {
    for (int e = tid; e < 16 * 64; e += 256) {
      int oo = e / 16, kk = e % 16;
      int c = c0 + kk, o = o0 + oo;
      Wt[kk][oo] = (c < C && o < O) ? W[(long)o * ldw + c] : 0.f;
    }
    for (int e = tid; e < 16 * 64; e += 256) {
      int kk = e / 64, nn = e % 64;
      int c = c0 + kk, n = n0 + nn;
      Xt[kk][nn] = (c < C && n < Np) ? X[(long)b * xStrideB + (long)c * Np + n] : 0.f;
    }
    __syncthreads();
    for (int kk = 0; kk < 16; ++kk) {
      float xv[4], wv[4];
      for (int i = 0; i < 4; ++i) xv[i] = Xt[kk][tn + 16 * i];
      for (int j = 0; j < 4; ++j) wv[j] = Wt[kk][to + 16 * j];
      for (int i = 0; i < 4; ++i)
        for (int j = 0; j < 4; ++j) acc[i][j] = fmaf(xv[i], wv[j], acc[i][j]);
    }
    __syncthreads();
  }
  float vm[4];
  for (int j = 0; j < 4; ++j) {
    int o = o0 + to + 16 * j;
    float gs = g[o] * BN_SCALE, bo = bb[o];
    float m = -INFINITY;
    for (int i = 0; i < 4; ++i) {
      float h = acc[i][j] * gs + bo;
      h = h >= 0.f ? h : 0.2f * h;
      m = fmaxf(m, h);
    }
    vm[j] = m;
  }
  for (int j = 0; j < 4; ++j) Xt[tn][to + 16 * j] = vm[j];
  __syncthreads();
  for (int s = 8; s > 0; s >>= 1) {
    if (tn < s)
      for (int j = 0; j < 4; ++j)
        Xt[tn][to + 16 * j] = fmaxf(Xt[tn][to + 16 * j], Xt[tn + s][to + 16 * j]);
    __syncthreads();
  }
  if (tn == 0)
    for (int j = 0; j < 4; ++j) {
      int o = o0 + to + 16 * j;
      partial[((long)b * gridDim.x + blockIdx.x) * O + o] = Xt[0][to + 16 * j];
    }
}

// ---------------- FPS (R8-proven): 4 waves, dist[8] in VGPRs, 1 barrier/iter ----------------
__global__ void __launch_bounds__(256, 1) fps_kernel(const float* __restrict__ xyz, int N, int M,
                                                     int* __restrict__ fpsIdx, float* __restrict__ node1) {
  #pragma clang fp contract(off)
  __shared__ float4 sp4[2048];
  __shared__ int fidx[512];
  __shared__ float wvs[2][4];
  __shared__ int   wis[2][4];
  int b = blockIdx.x, tid = threadIdx.x;
  int lane = tid & 63, w = tid >> 6;
  const float* xb = xyz + (long)b * 3 * N;
  for (int n = tid; n < N; n += 256) {
    sp4[((n & 7) << 8) | (n >> 3)] = make_float4(xb[n], xb[N + n], xb[2 * N + n], 0.f);
  }
  __syncthreads();
  float dist[8];
  #pragma unroll
  for (int i = 0; i < 8; ++i) dist[i] = 1e10f;
  int base = tid * 8;
  int last = 0;
  for (int it = 0; it < M; ++it) {
    int p = it & 1;
    if (tid == 0) fidx[it] = last;
    float4 lp = sp4[((last & 7) << 8) | (last >> 3)];
    float best = -INFINITY; int bi = N;
    #pragma unroll
    for (int i = 0; i < 8; ++i) {
      float4 pt = sp4[(i << 8) | tid];
      float dx = pt.x - lp.x, dy = pt.y - lp.y, dz = pt.z - lp.z;
      float dx2 = dx * dx, dy2 = dy * dy, dz2 = dz * dz;
      float d = (dx2 + dy2) + dz2;
      float dn = dist[i];
      if (d < dn) dn = d;
      dist[i] = dn;
      if (dn > best) { best = dn; bi = base + i; }
    }
    float gmax = best;
    #pragma unroll
    for (int off = 32; off > 0; off >>= 1) {
      float ov = __shfl_xor(gmax, off);
      gmax = fmaxf(gmax, ov);
    }
    unsigned long long mm = __ballot(best == gmax);
    int srcLane = (int)(__ffsll((long long)mm) - 1);
    int wbi = __shfl(bi, srcLane);
    if (lane == 0) { wvs[p][w] = gmax; wis[p][w] = wbi; }
    __syncthreads();
    float bv = wvs[p][0]; int bbi = wis[p][0];
    #pragma unroll
    for (int ww = 1; ww < 4; ++ww) {
      float ov = wvs[p][ww]; int oi = wis[p][ww];
      if (ov > bv || (ov == bv && oi < bbi)) { bv = ov; bbi = oi; }
    }
    last = bbi;
  }
  for (int e = tid; e < M; e += 256) fpsIdx[(long)b * M + e] = fidx[e];
  for (int e = tid; e < 3 * M; e += 256) {
    int c = e / M, i = e % M;
    int src = fidx[i];
    float4 pt = sp4[((src & 7) << 8) | (src >> 3)];
    node1[(long)b * 3 * M + e] = (c == 0) ? pt.x : (c == 1) ? pt.y : pt.z;
  }
}

// ---------------- xmfill: fused nf1 gather + aggregate gathermax ----------------
__global__ void xmfill_kernel(const float* __restrict__ xt1, int N,
                              const int* __restrict__ fpsI,
                              const int* __restrict__ idxA, int k, int M,
                              float* __restrict__ xm, int B) {
  long t = (long)blockIdx.x * blockDim.x + threadIdx.x;
  long total = (long)B * 128 * M;
  if (t >= total) return;
  int i = (int)(t % M);
  int c = (int)((t / M) % 128);
  int b = (int)(t / ((long)128 * M));
  const float* xb = xt1 + (long)b * 128 * N + (long)c * N;
  float* xmB = xm + (long)b * 256 * M;
  xmB[(long)c * M + i] = xb[fpsI[(long)b * M + i]];
  const int* ip = idxA + ((long)b * M + i) * k;
  float best = -INFINITY;
  for (int kk = 0; kk < k; ++kk) best = fmaxf(best, xb[ip[kk]]);
  xmB[(long)(128 + c) * M + i] = best;
}

// ---------------- head: fused colmax_finish + 3-layer MLP ----------------
__global__ void head_kernel(const float* __restrict__ partA, int NTa,
                            const float* __restrict__ partB, int NTb,
                            const float* __restrict__ Wl1, const float* __restrict__ g6, const float* __restrict__ b6,
                            const float* __restrict__ Wl2, const float* __restrict__ bl2,
                            const float* __restrict__ g7, const float* __restrict__ b7,
                            const float* __restrict__ Wl3, const float* __restrict__ bl3,
                            float* __restrict__ logits) {
  __shared__ float v[2048];
  __shared__ float h1[512];
  __shared__ float h2[256];
  int b = blockIdx.x, tid = threadIdx.x;
  for (int o = tid; o < 1024; o += 256) {
    float m = -INFINITY;
    for (int t = 0; t < NTa; ++t) m = fmaxf(m, partA[((long)b * NTa + t) * 1024 + o]);
    v[o] = m;
    float m2 = -INFINITY;
    for (int t = 0; t < NTb; ++t) m2 = fmaxf(m2, partB[((long)b * NTb + t) * 1024 + o]);
    v[1024 + o] = m2;
  }
  __syncthreads();
  for (int o = tid; o < 512; o += 256) {
    const float* wr = Wl1 + (long)o * 2048;
    float s = 0.f;
    for (int c = 0; c < 2048; c += 4) {
      float4 w4 = *(const float4*)(wr + c);
      s = fmaf(w4.x, v[c], s); s = fmaf(w4.y, v[c + 1], s);
      s = fmaf(w4.z, v[c + 2], s); s = fmaf(w4.w, v[c + 3], s);
    }
    float h = s * (g6[o] * BN_SCALE) + b6[o];
    h1[o] = h >= 0.f ? h : 0.2f * h;
  }
  __syncthreads();
  for (int o = tid; o < 256; o += 256) {
    const float* wr = Wl2 + (long)o * 512;
    float s = 0.f;
    for (int c = 0; c < 512; c += 4) {
      float4 w4 = *(const float4*)(wr + c);
      s = fmaf(w4.x, h1[c], s); s = fmaf(w4.y, h1[c + 1], s);
      s = fmaf(w4.z, h1[c + 2], s); s = fmaf(w4.w, h1[c + 3], s);
    }
    s += bl2[o];
    float h = s * (g7[o] * BN_SCALE) + b7[o];
    h2[o] = h >= 0.f ? h : 0.2f * h;
  }
  __syncthreads();
  if (tid < 40) {
    const float* wr = Wl3 + (long)tid * 256;
    float s = 0.f;
    for (int c = 0; c < 256; ++c) s = fmaf(wr[c], h2[c], s);
    logits[(long)b * 40 + tid] = s + bl3[tid];
  }
}

extern "C" void kernel_launch(void* const* d_in, const int* in_sizes, int n_in,
                              void* d_out, int out_size, void* d_ws, size_t ws_size,
                              hipStream_t stream) {
  const float* x   = (const float*)d_in[0];
  const float* W1  = (const float*)d_in[1];
  const float* g1  = (const float*)d_in[2];
  const float* b1  = (const float*)d_in[3];
  const float* W2  = (const float*)d_in[4];
  const float* g2  = (const float*)d_in[5];
  const float* b2  = (const float*)d_in[6];
  const float* W2m = (const float*)d_in[7];
  const float* g2m = (const float*)d_in[8];
  const float* b2m = (const float*)d_in[9];
  const float* W3  = (const float*)d_in[10];
  const float* g3  = (const float*)d_in[11];
  const float* b3  = (const float*)d_in[12];
  const float* W4  = (const float*)d_in[13];
  const float* g4  = (const float*)d_in[14];
  const float* b4  = (const float*)d_in[15];
  const float* W5  = (const float*)d_in[16];
  const float* g5  = (const float*)d_in[17];
  const float* b5  = (const float*)d_in[18];
  const float* Wl1 = (const float*)d_in[19];
  const float* g6  = (const float*)d_in[20];
  const float* b6  = (const float*)d_in[21];
  const float* Wl2 = (const float*)d_in[22];
  const float* bl2 = (const float*)d_in[23];
  const float* g7  = (const float*)d_in[24];
  const float* b7  = (const float*)d_in[25];
  const float* Wl3 = (const float*)d_in[26];
  const float* bl3 = (const float*)d_in[27];
  float* outF = (float*)d_out;

  const int B = 8, N = 2048, K = 20, M = 512, K2 = 10;

  float* ws     = (float*)d_ws;
  float* xt1    = ws;                               // (B,128,N)
  float* xm     = xt1 + (size_t)B * 128 * N;        // (B,256,M)
  float* xc     = xm  + (size_t)B * 256 * M;        // (B,512,M)
  float* Pt     = xc  + (size_t)B * 512 * M;        // max(B*N*64, B*M*256)
  float* St     = Pt  + (size_t)B * N * 64;
  float* partA  = St  + (size_t)B * N * 64;         // (B,32,1024)
  float* partB  = partA + (size_t)B * 32 * 1024;    // (B,8,1024)
  int*   idxK   = (int*)(partB + (size_t)B * 8 * 1024);  // (B,N,K)
  int*   fpsI   = idxK + (size_t)B * N * K;         // (B,M)
  int*   idxAgg = fpsI + (size_t)B * M;             // (B,M,K)

  float* logits = outF;        // (B,40)
  float* node1  = outF + 320;  // (B,3,M)

  dim3 t256(256);

  // stage 1: knn1 + gemmPS1 -> ecf1 -> xt1 ch0..63
  knn16_kernel<2048, 64><<<dim3(N / 16, B), t256, 0, stream>>>(x, 3 * N, x, 3 * N, 3, N, K, idxK);
  gemmPS_kernel<<<dim3(N / 64, 1, B), t256, 0, stream>>>(x, 3 * N, 3, N, W1, 6, 64, Pt, St);
  ecfinish_kernel<<<dim3(N / 4, B), dim3(64, 4), 0, stream>>>(Pt, St, idxK, K, 64, N, g1, b1, xt1, (long)128 * N);

  // fps -> fpsI, node1 ; then agg-knn -> idxAgg (separate buffer, no ordering hazard)
  fps_kernel<<<dim3(B), t256, 0, stream>>>(x, N, M, fpsI, node1);
  knn16_kernel<2048, 64><<<dim3(M / 16, B), t256, 0, stream>>>(node1, 3 * M, x, 3 * N, 3, M, K, idxAgg);

  // stage 2: knn2 + gemmPS2 -> ecf2 -> xt1 ch64..127
  knn16_kernel<2048, 64><<<dim3(N / 16, B), t256, 0, stream>>>(xt1, (long)128 * N, xt1, (long)128 * N, 64, N, K, idxK);
  gemmPS_kernel<<<dim3(N / 64, 1, B), t256, 0, stream>>>(xt1, 128 * N, 64, N, W2, 128, 64, Pt, St);
  ecfinish_kernel<<<dim3(N / 4, B), dim3(64, 4), 0, stream>>>(Pt, St, idxK, K, 64, N, g2, b2,
                                                              xt1 + (size_t)64 * N, (long)128 * N);

  // vf partials + xm fill
  gemm_colmax_kernel<<<dim3(N / 64, 1024 / 64, B), t256, 0, stream>>>(xt1, 128 * N, 128, N, W2m, 128, 1024,
                                                                      g2m, b2m, partA);
  xmfill_kernel<<<dim3((B * 128 * M + 255) / 256), t256, 0, stream>>>(xt1, N, fpsI, idxAgg, K, M, xm, B);

  // stage 3: knn3 + gemmPS3 -> ecf3 -> xc ch0..255
  knn16_kernel<512, 256><<<dim3(M / 16, B), t256, 0, stream>>>(xm, (long)256 * M, xm, (long)256 * M, 256, M, K2, idxK);
  gemmPS_kernel<<<dim3(M / 64, 256 / 64, B), t256, 0, stream>>>(xm, 256 * M, 256, M, W3, 512, 256, Pt, St);
  ecfinish_kernel<<<dim3(M, B), dim3(256, 1), 0, stream>>>(Pt, St, idxK, K2, 256, M, g3, b3, xc, (long)512 * M);

  // stage 4: knn4 + gemmPS4 -> ecf4 -> xc ch256..511
  knn16_kernel<512, 256><<<dim3(M / 16, B), t256, 0, stream>>>(xc, (long)512 * M, xc, (long)512 * M, 256, M, K2, idxK);
  gemmPS_kernel<<<dim3(M / 64, 256 / 64, B), t256, 0, stream>>>(xc, 512 * M, 256, M, W4, 512, 256, Pt, St);
  ecfinish_kernel<<<dim3(M, B), dim3(256, 1), 0, stream>>>(Pt, St, idxK, K2, 256, M, g4, b4,
                                                           xc + (size_t)256 * M, (long)512 * M);

  // vs partials
  gemm_colmax_kernel<<<dim3(M / 64, 1024 / 64, B), t256, 0, stream>>>(xc, 512 * M, 512, M, W5, 512, 1024,
                                                                      g5, b5, partB);

  // head
  head_kernel<<<dim3(B), t256, 0, stream>>>(partA, 32, partB, 8,
                                            Wl1, g6, b6, Wl2, bl2, g7, b7, Wl3, bl3, logits);
}